// Round 7
// baseline (849.959 us; speedup 1.0000x reference)
//
#include <hip/hip_runtime.h>
#include <cmath>

// ---------------- constants ----------------
// B=4096, M=8, HSS=128, HID=1024, NIN=8, DIN=128, IH=4, KDIM=64, VDIM=128,
// T=4, TOPK=4, CH=4, CDK=32, CDV=32
#define NB 4096
#define HIDX 1024

// d_out layout (floats): hx_out[4194304] | mask_full[4194304] | block_mask[32768] | temp_att[131072]

__device__ __forceinline__ float sigm(float x) { return 1.0f / (1.0f + expf(-x)); }

// ---------------- K0: weight prep ----------------
// Wvm[i][d]   = mean over 4 heads of Wv_in[i][h*128+d]                (128x128)
// Wih3[t][i][j][g] = W_ih[t][g*128+j][i]   (4x128x128x3)
// Whh3[t][i][j][g] = W_hh[t][g*128+j][i]   (4x128x128x3)
__global__ __launch_bounds__(256) void k0_prep(
    const float* __restrict__ Wv_in, const float* __restrict__ W_ih,
    const float* __restrict__ W_hh, float* __restrict__ Wvm,
    float* __restrict__ Wih3, float* __restrict__ Whh3)
{
    int idx = blockIdx.x * 256 + threadIdx.x;
    if (idx < 16384) {
        int i = idx >> 7, d = idx & 127;
        const float* p = Wv_in + i * 512 + d;
        Wvm[idx] = 0.25f * (p[0] + p[128] + p[256] + p[384]);
    } else if (idx < 16384 + 196608) {
        int o = idx - 16384;
        int g = o % 3, rem = o / 3;
        int j = rem & 127, rem2 = rem >> 7;
        int i = rem2 & 127, t = rem2 >> 7;
        Wih3[o] = W_ih[(t * 384 + g * 128 + j) * 128 + i];
    } else if (idx < 16384 + 2 * 196608) {
        int o = idx - 16384 - 196608;
        int g = o % 3, rem = o / 3;
        int j = rem & 127, rem2 = rem >> 7;
        int i = rem2 & 127, t = rem2 >> 7;
        Whh3[o] = W_hh[(t * 384 + g * 128 + j) * 128 + i];
    }
}

// ---------------- K1: input attention ----------------
// one batch element per workgroup, 256 threads
__global__ __launch_bounds__(256) void k1_input_attn(
    const float* __restrict__ inp, const float* __restrict__ hx,
    const float* __restrict__ Wq, const float* __restrict__ Wk,
    const float* __restrict__ Wvm,
    float* iu /*inp_use out (aliases mask_full slot)*/,
    float* __restrict__ maskp, float* __restrict__ block_mask)
{
    int b = blockIdx.x;
    int tid = threadIdx.x;
    __shared__ float hT[128][8];   // [feat][m]
    __shared__ float xT[128][8];   // [feat][n]
    __shared__ float QT[256][8];   // [c][m]
    __shared__ float KT[256][8];   // [c][n]
    __shared__ float V[8][128];    // [n][d]
    __shared__ float S[8][8];
    __shared__ float P[8][9];
    __shared__ float nnull[8];
    __shared__ float maskS[8];

    { // stage h,x transposed
        float4 hv = reinterpret_cast<const float4*>(hx + b * HIDX)[tid];
        float4 xv = reinterpret_cast<const float4*>(inp + b * HIDX)[tid];
        int g = tid * 4;
        int m = g >> 7, i0 = g & 127;
        hT[i0 + 0][m] = hv.x; hT[i0 + 1][m] = hv.y; hT[i0 + 2][m] = hv.z; hT[i0 + 3][m] = hv.w;
        xT[i0 + 0][m] = xv.x; xT[i0 + 1][m] = xv.y; xT[i0 + 2][m] = xv.z; xT[i0 + 3][m] = xv.w;
    }
    __syncthreads();
    { // Q = h@Wq, K = x@Wk : thread owns column j = tid (256 cols)
        int j = tid;
        float aq[8] = {0, 0, 0, 0, 0, 0, 0, 0};
        float ak[8] = {0, 0, 0, 0, 0, 0, 0, 0};
        for (int i = 0; i < 128; ++i) {
            float wq = Wq[i * 256 + j];
            float wk = Wk[i * 256 + j];
#pragma unroll
            for (int m = 0; m < 8; ++m) {
                aq[m] = fmaf(hT[i][m], wq, aq[m]);
                ak[m] = fmaf(xT[i][m], wk, ak[m]);
            }
        }
#pragma unroll
        for (int m = 0; m < 8; ++m) { QT[j][m] = aq[m]; KT[j][m] = ak[m]; }
    }
    { // V = x@Wvm : thread owns (d = tid&127, 4 n's)
        int d = tid & 127;
        int n0 = (tid >> 7) * 4;
        float av[4] = {0, 0, 0, 0};
        for (int i = 0; i < 128; ++i) {
            float w = Wvm[i * 128 + d];
#pragma unroll
            for (int p = 0; p < 4; ++p) av[p] = fmaf(xT[i][n0 + p], w, av[p]);
        }
#pragma unroll
        for (int p = 0; p < 4; ++p) V[n0 + p][d] = av[p];
    }
    __syncthreads();
    if (tid < 64) { // scores: full 256-dot / 32 (collapses head mean)
        int m = tid >> 3, n = tid & 7;
        float s = 0.0f;
        for (int c = 0; c < 256; ++c) s = fmaf(QT[c][m], KT[c][n], s);
        S[m][n] = s * (1.0f / 32.0f);
    }
    __syncthreads();
    if (tid < 8) { // softmax over 9 (null col score == 0), notnull
        int m = tid;
        float mx = 0.0f; // null score = 0 participates in max
        for (int n = 0; n < 8; ++n) mx = fmaxf(mx, S[m][n]);
        float en = expf(0.0f - mx);
        float sum = en;
        float e[8];
        for (int n = 0; n < 8; ++n) { e[n] = expf(S[m][n] - mx); sum += e[n]; }
        float inv = 1.0f / sum;
        for (int n = 0; n < 8; ++n) P[m][n] = e[n] * inv;
        nnull[m] = 1.0f - en * inv;
    }
    __syncthreads();
    if (tid == 0) { // strict top-4 (ties -> lower index, matches lax.top_k)
        unsigned sel = 0;
        for (int s = 0; s < 4; ++s) {
            int best = 0; float bv = -3.0e38f;
            for (int m = 0; m < 8; ++m)
                if (!(sel & (1u << m)) && nnull[m] > bv) { bv = nnull[m]; best = m; }
            sel |= 1u << best;
        }
        for (int m = 0; m < 8; ++m) maskS[m] = (sel & (1u << m)) ? 1.0f : 0.0f;
    }
    __syncthreads();
    { // out = P@V * mask -> inp_use
        int m = tid >> 5;
        int d0 = (tid & 31) * 4;
        float acc[4] = {0, 0, 0, 0};
#pragma unroll
        for (int n = 0; n < 8; ++n) {
            float p = P[m][n];
#pragma unroll
            for (int q = 0; q < 4; ++q) acc[q] = fmaf(p, V[n][d0 + q], acc[q]);
        }
        float mk = maskS[m];
        reinterpret_cast<float4*>(iu + b * HIDX + m * 128 + d0)[0] =
            make_float4(acc[0] * mk, acc[1] * mk, acc[2] * mk, acc[3] * mk);
    }
    if (tid < 8) {
        maskp[b * 8 + tid] = maskS[tid];
        block_mask[b * 8 + tid] = maskS[tid];
    }
}

// ---------------- K2: shared block GRU ----------------
// 2 batch elements (16 rows) per workgroup, 256 threads.
// LDS-pipe fix: inner loop reads operands as float2 (ds_read_b64), halving
// LDS instruction count (was 16 b32/iter ~ 93 cyc ~ parity with 96 cyc FMA).
// Weights prefetched one 2-iter chunk ahead (global/L2 latency hiding).
__global__ __launch_bounds__(256) void k2_gru(
    float* iu /*in: inp_use, out: mask_full (same memory)*/,
    const float* __restrict__ hx,
    const float* __restrict__ Wih3, const float* __restrict__ Whh3,
    const float* __restrict__ b_ih, const float* __restrict__ b_hh,
    const float* __restrict__ W_read, const float* __restrict__ W_write,
    const float* __restrict__ maskp,
    float* __restrict__ hnew_out /*d_out hx slot*/, float* __restrict__ temp_att)
{
    int b0 = blockIdx.x * 2;
    int tid = threadIdx.x;
    __shared__ float xs[16][128];      // natural [row][feat]
    __shared__ float hs[16][128];
    __shared__ float hnext[16][516];   // stride 516: rows land on distinct banks
    __shared__ float hread[16][16];    // also reused for att (first 4 cols)
    // wkey aliases the (dead-after-GRU) xs buffer: 16*4*16 floats = 4 KB <= 8 KB
    float (*wkey)[4][16] = reinterpret_cast<float (*)[4][16]>(&xs[0][0]);

    { // stage natural (conflict-free float4 writes); emit mask_full in place
#pragma unroll
        for (int q = 0; q < 2; ++q) {
            int idx = tid + q * 256;           // 0..511
            float4 xv = reinterpret_cast<const float4*>(iu + b0 * HIDX)[idx];
            float4 hv = reinterpret_cast<const float4*>(hx + b0 * HIDX)[idx];
            int r = idx >> 5, c = (idx & 31) * 4;
            *reinterpret_cast<float4*>(&xs[r][c]) = xv;
            *reinterpret_cast<float4*>(&hs[r][c]) = hv;
            float mkv = maskp[b0 * 8 + r];
            reinterpret_cast<float4*>(iu + b0 * HIDX)[idx] = make_float4(mkv, mkv, mkv, mkv);
        }
    }
    __syncthreads();
    int j = tid & 127;
    int r0 = (tid >> 7) * 8;
    for (int t = 0; t < 4; ++t) {
        float a0[8] = {0,0,0,0,0,0,0,0}, a1[8] = {0,0,0,0,0,0,0,0}, a2[8] = {0,0,0,0,0,0,0,0};
        float a3[8] = {0,0,0,0,0,0,0,0}, a4[8] = {0,0,0,0,0,0,0,0}, a5[8] = {0,0,0,0,0,0,0,0};
        const float* pih = Wih3 + (t * 16384 + j) * 3;   // stride per i: 384 floats
        const float* phh = Whh3 + (t * 16384 + j) * 3;
        // weights for a 2-iteration chunk: [gir,giz,gin,ghr,ghz,ghn] x {i, i+1}
        float cw[12], nw[12];
#pragma unroll
        for (int k = 0; k < 3; ++k) { cw[k] = pih[k]; cw[3 + k] = phh[k]; }
#pragma unroll
        for (int k = 0; k < 3; ++k) { cw[6 + k] = pih[384 + k]; cw[9 + k] = phh[384 + k]; }
#pragma unroll 2
        for (int c = 0; c < 64; ++c) {
            { // prefetch next chunk's weights (wraps to 0 on last; redundant, harmless)
                int ip = ((c + 1) & 63) * 2;
                const float* pa = pih + ip * 384;
                const float* pb = phh + ip * 384;
#pragma unroll
                for (int k = 0; k < 3; ++k) { nw[k] = pa[k]; nw[3 + k] = pb[k]; }
#pragma unroll
                for (int k = 0; k < 3; ++k) { nw[6 + k] = pa[384 + k]; nw[9 + k] = pb[384 + k]; }
            }
            int i = c * 2;
            float2 xv[8], hv[8];
#pragma unroll
            for (int p = 0; p < 8; ++p) {
                xv[p] = *reinterpret_cast<const float2*>(&xs[r0 + p][i]);
                hv[p] = *reinterpret_cast<const float2*>(&hs[r0 + p][i]);
            }
#pragma unroll
            for (int p = 0; p < 8; ++p) {
                a0[p] = fmaf(xv[p].x, cw[0], a0[p]);
                a1[p] = fmaf(xv[p].x, cw[1], a1[p]);
                a2[p] = fmaf(xv[p].x, cw[2], a2[p]);
                a3[p] = fmaf(hv[p].x, cw[3], a3[p]);
                a4[p] = fmaf(hv[p].x, cw[4], a4[p]);
                a5[p] = fmaf(hv[p].x, cw[5], a5[p]);
                a0[p] = fmaf(xv[p].y, cw[6], a0[p]);
                a1[p] = fmaf(xv[p].y, cw[7], a1[p]);
                a2[p] = fmaf(xv[p].y, cw[8], a2[p]);
                a3[p] = fmaf(hv[p].y, cw[9], a3[p]);
                a4[p] = fmaf(hv[p].y, cw[10], a4[p]);
                a5[p] = fmaf(hv[p].y, cw[11], a5[p]);
            }
#pragma unroll
            for (int k = 0; k < 12; ++k) cw[k] = nw[k];
        }
        float bir = b_ih[t * 384 + j], biz = b_ih[t * 384 + 128 + j], bin = b_ih[t * 384 + 256 + j];
        float bhr = b_hh[t * 384 + j], bhz = b_hh[t * 384 + 128 + j], bhn = b_hh[t * 384 + 256 + j];
#pragma unroll
        for (int p = 0; p < 8; ++p) {
            int r = r0 + p;
            float rr = sigm(a0[p] + bir + a3[p] + bhr);
            float zz = sigm(a1[p] + biz + a4[p] + bhz);
            float nn = tanhf(a2[p] + bin + rr * (a5[p] + bhn));
            hnext[r][t * 128 + j] = (1.0f - zz) * nn + zz * hs[r][j];
        }
    }
    __syncthreads();
    { // h_read (16x16) into hread; then w_key into wkey (aliases xs, dead now)
        int r = tid >> 4, k = tid & 15;
        float acc = 0.0f;
        for (int h = 0; h < 128; ++h) acc = fmaf(hs[r][h], W_read[h * 16 + k], acc);
        hread[r][k] = acc;
        for (int t = 0; t < 4; ++t) {
            float a2v = 0.0f;
            for (int h = 0; h < 128; ++h)
                a2v = fmaf(hnext[r][t * 128 + h], W_write[(t * 128 + h) * 16 + k], a2v);
            wkey[r][t][k] = a2v;
        }
    }
    __syncthreads();
    if (tid < 16) { // template softmax; att stored back into hread[r][0..3]
        int r = tid;
        float lg[4];
        for (int t = 0; t < 4; ++t) {
            float s = 0.0f;
            for (int k = 0; k < 16; ++k) s = fmaf(hread[r][k], wkey[r][t][k], s);
            lg[t] = s * 0.25f;
        }
        float mx = fmaxf(fmaxf(lg[0], lg[1]), fmaxf(lg[2], lg[3]));
        float e[4], sum = 0.0f;
        for (int t = 0; t < 4; ++t) { e[t] = expf(lg[t] - mx); sum += e[t]; }
        float inv = 1.0f / sum;
        float att[4];
        for (int t = 0; t < 4; ++t) att[t] = e[t] * inv;
        for (int t = 0; t < 4; ++t) {
            hread[r][t] = att[t];
            temp_att[(b0 * 8 + r) * 4 + t] = att[t];
        }
    }
    __syncthreads();
    { // hnew = sum_t att[t] * hnext[t]
        int r = tid >> 4;
        int h0 = (tid & 15) * 8;
        float o[8] = {0, 0, 0, 0, 0, 0, 0, 0};
#pragma unroll
        for (int t = 0; t < 4; ++t) {
            float a = hread[r][t];
#pragma unroll
            for (int q = 0; q < 8; ++q) o[q] = fmaf(a, hnext[r][t * 128 + h0 + q], o[q]);
        }
        float* dst = hnew_out + (b0 + (r >> 3)) * HIDX + (r & 7) * 128 + h0;
        reinterpret_cast<float4*>(dst)[0] = make_float4(o[0], o[1], o[2], o[3]);
        reinterpret_cast<float4*>(dst)[1] = make_float4(o[4], o[5], o[6], o[7]);
    }
}

// ---------------- K3: comm attention + final select ----------------
// 2 batch elements per workgroup; reads hnew from hio, writes hx_out in place
__global__ __launch_bounds__(256) void k3_comm(
    const float* __restrict__ hx, const float* __restrict__ maskp,
    const float* __restrict__ Wq_c, const float* __restrict__ bq_c,
    const float* __restrict__ Wk_c, const float* __restrict__ bk_c,
    const float* __restrict__ Wv_c, const float* __restrict__ bv_c,
    const float* __restrict__ W_fc, const float* __restrict__ b_fc,
    const float* __restrict__ W_g, const float* __restrict__ b_g,
    float* hio)
{
    int b0 = blockIdx.x * 2;
    int tid = threadIdx.x;
    __shared__ float hT[128][16];   // hnew transposed [feat][row]
    __shared__ float qT[128][16];   // [c][row]
    __shared__ float kT[128][16];
    __shared__ float vN[16][128];   // natural [row][c]
    __shared__ float P[2][4][8][8]; // [b'][ch][m][n]
    __shared__ float outT[128][16]; // [c][row]
    __shared__ float fco[16][128];
    __shared__ float gco[16][128];

    {
#pragma unroll
        for (int q = 0; q < 2; ++q) {
            int idx = tid + q * 256;
            float4 hv = reinterpret_cast<const float4*>(hio + b0 * HIDX)[idx];
            int g = idx * 4;
            int r = g >> 7, i0 = g & 127;
            hT[i0 + 0][r] = hv.x; hT[i0 + 1][r] = hv.y; hT[i0 + 2][r] = hv.z; hT[i0 + 3][r] = hv.w;
        }
    }
    __syncthreads();
    { // q,k,v = h@W + b : thread owns (b' = tid>>7, col jj = tid&127)
        int jj = tid & 127;
        int r0 = (tid >> 7) * 8;
        float aq[8] = {0,0,0,0,0,0,0,0}, ak[8] = {0,0,0,0,0,0,0,0}, av[8] = {0,0,0,0,0,0,0,0};
        for (int i = 0; i < 128; ++i) {
            float wq = Wq_c[i * 128 + jj];
            float wk = Wk_c[i * 128 + jj];
            float wv = Wv_c[i * 128 + jj];
#pragma unroll
            for (int p = 0; p < 8; ++p) {
                float h = hT[i][r0 + p];
                aq[p] = fmaf(h, wq, aq[p]);
                ak[p] = fmaf(h, wk, ak[p]);
                av[p] = fmaf(h, wv, av[p]);
            }
        }
        float bq = bq_c[jj], bk = bk_c[jj], bv = bv_c[jj];
#pragma unroll
        for (int p = 0; p < 8; ++p) {
            qT[jj][r0 + p] = aq[p] + bq;
            kT[jj][r0 + p] = ak[p] + bk;
            vN[r0 + p][jj] = av[p] + bv;
        }
    }
    __syncthreads();
    if (tid < 64) { // per-head scores + softmax: (b',ch,m)
        int bp = tid >> 5, ch = (tid >> 3) & 3, m = tid & 7;
        int r = bp * 8 + m;
        float s[8] = {0, 0, 0, 0, 0, 0, 0, 0};
        for (int d = 0; d < 32; ++d) {
            float qv = qT[ch * 32 + d][r];
#pragma unroll
            for (int n = 0; n < 8; ++n) s[n] = fmaf(qv, kT[ch * 32 + d][bp * 8 + n], s[n]);
        }
        const float scl = 0.17677669529663687f; // 1/sqrt(32)
        float mx = -3.0e38f;
        for (int n = 0; n < 8; ++n) { s[n] *= scl; mx = fmaxf(mx, s[n]); }
        float e[8], sum = 0.0f;
        for (int n = 0; n < 8; ++n) { e[n] = expf(s[n] - mx); sum += e[n]; }
        float inv = 1.0f / sum;
        for (int n = 0; n < 8; ++n) P[bp][ch][m][n] = e[n] * inv;
    }
    __syncthreads();
    { // out = attn @ v  -> outT
        int r = tid >> 4, bp = r >> 3, m = r & 7;
        int c0 = (tid & 15) * 8, ch = c0 >> 5;
        float acc[8] = {0, 0, 0, 0, 0, 0, 0, 0};
#pragma unroll
        for (int n = 0; n < 8; ++n) {
            float p = P[bp][ch][m][n];
#pragma unroll
            for (int q = 0; q < 8; ++q) acc[q] = fmaf(p, vN[bp * 8 + n][c0 + q], acc[q]);
        }
#pragma unroll
        for (int q = 0; q < 8; ++q) outT[c0 + q][r] = acc[q];
    }
    __syncthreads();
    { // fc and gate GEMMs: (mat = tid>>7, jj = tid&127), 16 rows each
        int mat = tid >> 7, jj = tid & 127;
        const float* W = mat ? W_g : W_fc;
        float acc[16] = {0,0,0,0,0,0,0,0,0,0,0,0,0,0,0,0};
        for (int i = 0; i < 128; ++i) {
            float w = W[i * 128 + jj];
#pragma unroll
            for (int r = 0; r < 16; ++r) acc[r] = fmaf(outT[i][r], w, acc[r]);
        }
        if (mat == 0) {
            float bb = b_fc[jj];
            for (int r = 0; r < 16; ++r) fco[r][jj] = acc[r] + bb;
        } else {
            float bb = b_g[jj];
            for (int r = 0; r < 16; ++r) gco[r][jj] = acc[r] + bb;
        }
    }
    __syncthreads();
    { // final: att_out = sigm(gate)*tanh(fc); hx_out = mask ? hnew+att_out : hx
        int r = tid >> 4, j0 = (tid & 15) * 8;
        int b = b0 + (r >> 3), m = r & 7;
        float mk = maskp[b * 8 + m];
        float res[8];
#pragma unroll
        for (int q = 0; q < 8; ++q) {
            int jj = j0 + q;
            float ao = sigm(gco[r][jj]) * tanhf(fco[r][jj]);
            float hn = hT[jj][r] + ao;
            float ho = hx[b * HIDX + m * 128 + jj];
            res[q] = mk * hn + (1.0f - mk) * ho;
        }
        float* dst = hio + b * HIDX + m * 128 + j0;
        reinterpret_cast<float4*>(dst)[0] = make_float4(res[0], res[1], res[2], res[3]);
        reinterpret_cast<float4*>(dst)[1] = make_float4(res[4], res[5], res[6], res[7]);
    }
}

// ---------------- launch ----------------
extern "C" void kernel_launch(void* const* d_in, const int* in_sizes, int n_in,
                              void* d_out, int out_size, void* d_ws, size_t ws_size,
                              hipStream_t stream)
{
    const float* inp     = (const float*)d_in[0];
    const float* hx      = (const float*)d_in[1];
    const float* Wq_in   = (const float*)d_in[3];
    const float* Wk_in   = (const float*)d_in[4];
    const float* Wv_in   = (const float*)d_in[5];
    const float* W_ih    = (const float*)d_in[6];
    const float* b_ih    = (const float*)d_in[7];
    const float* W_hh    = (const float*)d_in[8];
    const float* b_hh    = (const float*)d_in[9];
    const float* W_read  = (const float*)d_in[10];
    const float* W_write = (const float*)d_in[11];
    const float* Wq_c    = (const float*)d_in[12];
    const float* bq_c    = (const float*)d_in[13];
    const float* Wk_c    = (const float*)d_in[14];
    const float* bk_c    = (const float*)d_in[15];
    const float* Wv_c    = (const float*)d_in[16];
    const float* bv_c    = (const float*)d_in[17];
    const float* W_fc    = (const float*)d_in[18];
    const float* b_fc    = (const float*)d_in[19];
    const float* W_g     = (const float*)d_in[20];
    const float* b_g     = (const float*)d_in[21];

    float* out        = (float*)d_out;
    float* hx_out     = out;                 // B*1024
    float* mask_full  = out + 4194304;       // B*1024 (also temp home of inp_use)
    float* block_mask = out + 8388608;       // B*8
    float* temp_att   = out + 8421376;       // B*8*4

    float* ws    = (float*)d_ws;
    float* Wvm   = ws;                       // 16384
    float* Wih3  = Wvm + 16384;              // 196608
    float* Whh3  = Wih3 + 196608;            // 196608
    float* maskp = Whh3 + 196608;            // 32768
    // total ws: ~1.73 MB

    k0_prep<<<1600, 256, 0, stream>>>(Wv_in, W_ih, W_hh, Wvm, Wih3, Whh3);
    k1_input_attn<<<NB, 256, 0, stream>>>(inp, hx, Wq_in, Wk_in, Wvm,
                                          mask_full /*inp_use*/, maskp, block_mask);
    k2_gru<<<NB / 2, 256, 0, stream>>>(mask_full /*inp_use -> mask_full*/, hx,
                                       Wih3, Whh3, b_ih, b_hh, W_read, W_write,
                                       maskp, hx_out /*hnew*/, temp_att);
    k3_comm<<<NB / 2, 256, 0, stream>>>(hx, maskp, Wq_c, bq_c, Wk_c, bk_c,
                                        Wv_c, bv_c, W_fc, b_fc, W_g, b_g, hx_out);
}

// Round 8
// 471.852 us; speedup vs baseline: 1.8013x; 1.8013x over previous
//
#include <hip/hip_runtime.h>
#include <cmath>

// ---------------- constants ----------------
// B=4096, M=8, HSS=128, HID=1024, T=4, CH=4, CDK=32, CDV=32
#define NB 4096
#define HIDX 1024

// d_out layout (floats): hx_out[4194304] | mask_full[4194304] | block_mask[32768] | temp_att[131072]

__device__ __forceinline__ float sigm(float x) { return 1.0f / (1.0f + expf(-x)); }

// round-to-nearest-even fp32 -> bf16 bits
__device__ __forceinline__ unsigned short f2bf(float f) {
    unsigned u = __float_as_uint(f);
    unsigned r = (u + 0x7FFFu + ((u >> 16) & 1u)) >> 16;
    return (unsigned short)r;
}

typedef __attribute__((ext_vector_type(8))) short short8v;  // 8 bf16
typedef __attribute__((ext_vector_type(4))) float f32x4;

// ---------------- K0: weight prep ----------------
// Wvm[i][d] = mean over 4 heads of Wv_in[i][h*128+d]  (128x128 fp32)
// Bpk: bf16 MFMA B-fragments for GRU weights.
//   block index = ((t*4+ks)*6+g)*8 + jt   (t templates, ks K-step of 32,
//   g in {ir,iz,in,hr,hz,hn}, jt = j-tile of 16)
//   within block: lane l (0..63), elem e (0..7):
//     k = ks*32 + 4*(l>>4) + (e&3) + (e&4 ? 16 : 0)   [k-perm cancels: same in A]
//     n = jt*16 + (l&15)   (j column)
//   value: g<3 -> W_ih[t][g*128+n][k] ; else W_hh[t][(g-3)*128+n][k]
__global__ __launch_bounds__(256) void k0_prep(
    const float* __restrict__ Wv_in, const float* __restrict__ W_ih,
    const float* __restrict__ W_hh, float* __restrict__ Wvm,
    unsigned short* __restrict__ Bpk)
{
    int idx = blockIdx.x * 256 + threadIdx.x;
    if (idx < 16384) {
        int i = idx >> 7, d = idx & 127;
        const float* p = Wv_in + i * 512 + d;
        Wvm[idx] = 0.25f * (p[0] + p[128] + p[256] + p[384]);
    } else if (idx < 16384 + 393216) {
        int o = idx - 16384;
        int e = o & 7, l = (o >> 3) & 63, blk = o >> 9;
        int jt = blk & 7, gq = blk >> 3;
        int g = gq % 6, q2 = gq / 6;
        int ks = q2 & 3, t = q2 >> 2;
        int k = ks * 32 + 4 * (l >> 4) + (e & 3) + ((e & 4) ? 16 : 0);
        int n = jt * 16 + (l & 15);
        float v = (g < 3) ? W_ih[(t * 384 + g * 128 + n) * 128 + k]
                          : W_hh[(t * 384 + (g - 3) * 128 + n) * 128 + k];
        Bpk[o] = f2bf(v);
    }
}

// ---------------- K1: input attention (unchanged, fp32) ----------------
__global__ __launch_bounds__(256) void k1_input_attn(
    const float* __restrict__ inp, const float* __restrict__ hx,
    const float* __restrict__ Wq, const float* __restrict__ Wk,
    const float* __restrict__ Wvm,
    float* iu /*inp_use out (aliases mask_full slot)*/,
    float* __restrict__ maskp, float* __restrict__ block_mask)
{
    int b = blockIdx.x;
    int tid = threadIdx.x;
    __shared__ float hT[128][8];
    __shared__ float xT[128][8];
    __shared__ float QT[256][8];
    __shared__ float KT[256][8];
    __shared__ float V[8][128];
    __shared__ float S[8][8];
    __shared__ float P[8][9];
    __shared__ float nnull[8];
    __shared__ float maskS[8];

    {
        float4 hv = reinterpret_cast<const float4*>(hx + b * HIDX)[tid];
        float4 xv = reinterpret_cast<const float4*>(inp + b * HIDX)[tid];
        int g = tid * 4;
        int m = g >> 7, i0 = g & 127;
        hT[i0 + 0][m] = hv.x; hT[i0 + 1][m] = hv.y; hT[i0 + 2][m] = hv.z; hT[i0 + 3][m] = hv.w;
        xT[i0 + 0][m] = xv.x; xT[i0 + 1][m] = xv.y; xT[i0 + 2][m] = xv.z; xT[i0 + 3][m] = xv.w;
    }
    __syncthreads();
    {
        int j = tid;
        float aq[8] = {0, 0, 0, 0, 0, 0, 0, 0};
        float ak[8] = {0, 0, 0, 0, 0, 0, 0, 0};
        for (int i = 0; i < 128; ++i) {
            float wq = Wq[i * 256 + j];
            float wk = Wk[i * 256 + j];
#pragma unroll
            for (int m = 0; m < 8; ++m) {
                aq[m] = fmaf(hT[i][m], wq, aq[m]);
                ak[m] = fmaf(xT[i][m], wk, ak[m]);
            }
        }
#pragma unroll
        for (int m = 0; m < 8; ++m) { QT[j][m] = aq[m]; KT[j][m] = ak[m]; }
    }
    {
        int d = tid & 127;
        int n0 = (tid >> 7) * 4;
        float av[4] = {0, 0, 0, 0};
        for (int i = 0; i < 128; ++i) {
            float w = Wvm[i * 128 + d];
#pragma unroll
            for (int p = 0; p < 4; ++p) av[p] = fmaf(xT[i][n0 + p], w, av[p]);
        }
#pragma unroll
        for (int p = 0; p < 4; ++p) V[n0 + p][d] = av[p];
    }
    __syncthreads();
    if (tid < 64) {
        int m = tid >> 3, n = tid & 7;
        float s = 0.0f;
        for (int c = 0; c < 256; ++c) s = fmaf(QT[c][m], KT[c][n], s);
        S[m][n] = s * (1.0f / 32.0f);
    }
    __syncthreads();
    if (tid < 8) {
        int m = tid;
        float mx = 0.0f;
        for (int n = 0; n < 8; ++n) mx = fmaxf(mx, S[m][n]);
        float en = expf(0.0f - mx);
        float sum = en;
        float e[8];
        for (int n = 0; n < 8; ++n) { e[n] = expf(S[m][n] - mx); sum += e[n]; }
        float inv = 1.0f / sum;
        for (int n = 0; n < 8; ++n) P[m][n] = e[n] * inv;
        nnull[m] = 1.0f - en * inv;
    }
    __syncthreads();
    if (tid == 0) {
        unsigned sel = 0;
        for (int s = 0; s < 4; ++s) {
            int best = 0; float bv = -3.0e38f;
            for (int m = 0; m < 8; ++m)
                if (!(sel & (1u << m)) && nnull[m] > bv) { bv = nnull[m]; best = m; }
            sel |= 1u << best;
        }
        for (int m = 0; m < 8; ++m) maskS[m] = (sel & (1u << m)) ? 1.0f : 0.0f;
    }
    __syncthreads();
    {
        int m = tid >> 5;
        int d0 = (tid & 31) * 4;
        float acc[4] = {0, 0, 0, 0};
#pragma unroll
        for (int n = 0; n < 8; ++n) {
            float p = P[m][n];
#pragma unroll
            for (int q = 0; q < 4; ++q) acc[q] = fmaf(p, V[n][d0 + q], acc[q]);
        }
        float mk = maskS[m];
        reinterpret_cast<float4*>(iu + b * HIDX + m * 128 + d0)[0] =
            make_float4(acc[0] * mk, acc[1] * mk, acc[2] * mk, acc[3] * mk);
    }
    if (tid < 8) {
        maskp[b * 8 + tid] = maskS[tid];
        block_mask[b * 8 + tid] = maskS[tid];
    }
}

// ---------------- K2: shared block GRU via MFMA ----------------
// 2 batch elements (16 rows = one M-tile) per WG, 256 threads = 4 waves.
// GI/GH via mfma_f32_16x16x32_bf16; gates + epilogue fp32 as before.
// Wave w owns j in [w*32, w*32+32) = 2 N-tiles; 6 gate accumulators per tile.
__global__ __launch_bounds__(256) void k2_gru(
    float* iu /*in: inp_use, out: mask_full (same memory)*/,
    const float* __restrict__ hx,
    const unsigned short* __restrict__ Bpk,
    const float* __restrict__ b_ih, const float* __restrict__ b_hh,
    const float* __restrict__ W_read, const float* __restrict__ W_write,
    const float* __restrict__ maskp,
    float* __restrict__ hnew_out, float* __restrict__ temp_att)
{
    int b0 = blockIdx.x * 2;
    int tid = threadIdx.x;
    __shared__ float hs[16][132];              // fp32 H rows, padded (bank spread)
    __shared__ unsigned short Af[2][4][64][8]; // A-frags [mat x|h][ks][lane][8 bf16]
    __shared__ float hnext[16][516];
    __shared__ float hread[16][16];
    // wkey aliases Af (dead after GEMM): 4 KB <= 8 KB
    float (*wkey)[4][16] = reinterpret_cast<float (*)[4][16]>(&Af[0][0][0][0]);

    // ---- stage: hs fp32, A-fragments bf16, emit mask_full in place ----
#pragma unroll
    for (int it = 0; it < 2; ++it) {
        int idx = tid + it * 256;              // 0..511 float4 slots
        int r = idx >> 5, q = idx & 31;        // row, float4-index (k0 = 4q)
        float4 xv = reinterpret_cast<const float4*>(iu + b0 * HIDX)[idx];
        float4 hv = reinterpret_cast<const float4*>(hx + b0 * HIDX)[idx];
        hs[r][4 * q + 0] = hv.x; hs[r][4 * q + 1] = hv.y;
        hs[r][4 * q + 2] = hv.z; hs[r][4 * q + 3] = hv.w;
        // (r, k-quad) -> (lane, elem) per the k-perm used in Bpk (consistent!)
        int ks = q >> 3, rem = q & 7, hi = rem >> 2, p = rem & 3;
        int l = p * 16 + r;
        *reinterpret_cast<ushort4*>(&Af[0][ks][l][hi * 4]) =
            make_ushort4(f2bf(xv.x), f2bf(xv.y), f2bf(xv.z), f2bf(xv.w));
        *reinterpret_cast<ushort4*>(&Af[1][ks][l][hi * 4]) =
            make_ushort4(f2bf(hv.x), f2bf(hv.y), f2bf(hv.z), f2bf(hv.w));
        float mkv = maskp[b0 * 8 + r];
        reinterpret_cast<float4*>(iu + b0 * HIDX)[idx] = make_float4(mkv, mkv, mkv, mkv);
    }
    __syncthreads();

    int lane = tid & 63, wid = tid >> 6;
    short8v ax[4], ah[4];
#pragma unroll
    for (int ks = 0; ks < 4; ++ks) {
        ax[ks] = *reinterpret_cast<const short8v*>(&Af[0][ks][lane][0]);
        ah[ks] = *reinterpret_cast<const short8v*>(&Af[1][ks][lane][0]);
    }
    int jl = wid * 32 + (lane & 15);   // j for jt=0 (add 16 for jt=1)
    int rbase = (lane >> 4) * 4;       // C/D: row = rbase + reg, col = lane&15

    for (int t = 0; t < 4; ++t) {
        f32x4 acc[2][6];
#pragma unroll
        for (int jt = 0; jt < 2; ++jt)
#pragma unroll
            for (int g = 0; g < 6; ++g)
                acc[jt][g] = (f32x4){0.f, 0.f, 0.f, 0.f};
#pragma unroll
        for (int ks = 0; ks < 4; ++ks) {
            const unsigned short* pb =
                Bpk + (size_t)((((t * 4 + ks) * 6) * 8 + wid * 2) * 512 + lane * 8);
#pragma unroll
            for (int g = 0; g < 6; ++g) {
                short8v bv0 = *reinterpret_cast<const short8v*>(pb + g * 4096);
                short8v bv1 = *reinterpret_cast<const short8v*>(pb + g * 4096 + 512);
                short8v a = (g < 3) ? ax[ks] : ah[ks];
                acc[0][g] = __builtin_amdgcn_mfma_f32_16x16x32_bf16(a, bv0, acc[0][g], 0, 0, 0);
                acc[1][g] = __builtin_amdgcn_mfma_f32_16x16x32_bf16(a, bv1, acc[1][g], 0, 0, 0);
            }
        }
        // gates (fp32) for this t
#pragma unroll
        for (int jt = 0; jt < 2; ++jt) {
            int j = jl + jt * 16;
            float bir = b_ih[t * 384 + j],       bhr = b_hh[t * 384 + j];
            float biz = b_ih[t * 384 + 128 + j], bhz = b_hh[t * 384 + 128 + j];
            float bin = b_ih[t * 384 + 256 + j], bhn = b_hh[t * 384 + 256 + j];
#pragma unroll
            for (int rg = 0; rg < 4; ++rg) {
                int row = rbase + rg;
                float ir  = acc[jt][0][rg] + bir;
                float iz  = acc[jt][1][rg] + biz;
                float inn = acc[jt][2][rg] + bin;
                float hr  = acc[jt][3][rg] + bhr;
                float hz  = acc[jt][4][rg] + bhz;
                float hn  = acc[jt][5][rg] + bhn;
                float rr = sigm(ir + hr);
                float zz = sigm(iz + hz);
                float nn = tanhf(inn + rr * hn);
                hnext[row][t * 128 + j] = (1.0f - zz) * nn + zz * hs[row][j];
            }
        }
    }
    __syncthreads();

    { // h_read (16x16) and w_key (16x4x16)
        int r = tid >> 4, k = tid & 15;
        float acc = 0.0f;
        for (int h2 = 0; h2 < 128; ++h2) acc = fmaf(hs[r][h2], W_read[h2 * 16 + k], acc);
        hread[r][k] = acc;
        for (int t = 0; t < 4; ++t) {
            float a2v = 0.0f;
            for (int h2 = 0; h2 < 128; ++h2)
                a2v = fmaf(hnext[r][t * 128 + h2], W_write[(t * 128 + h2) * 16 + k], a2v);
            wkey[r][t][k] = a2v;
        }
    }
    __syncthreads();
    if (tid < 16) { // template softmax; att into hread[r][0..3]
        int r = tid;
        float lg[4];
        for (int t = 0; t < 4; ++t) {
            float s = 0.0f;
            for (int k = 0; k < 16; ++k) s = fmaf(hread[r][k], wkey[r][t][k], s);
            lg[t] = s * 0.25f;
        }
        float mx = fmaxf(fmaxf(lg[0], lg[1]), fmaxf(lg[2], lg[3]));
        float e[4], sum = 0.0f;
        for (int t = 0; t < 4; ++t) { e[t] = expf(lg[t] - mx); sum += e[t]; }
        float inv = 1.0f / sum;
        float att[4];
        for (int t = 0; t < 4; ++t) att[t] = e[t] * inv;
        for (int t = 0; t < 4; ++t) {
            hread[r][t] = att[t];
            temp_att[(b0 * 8 + r) * 4 + t] = att[t];
        }
    }
    __syncthreads();
    { // hnew = sum_t att[t] * hnext[t]
        int r = tid >> 4;
        int h0 = (tid & 15) * 8;
        float o[8] = {0, 0, 0, 0, 0, 0, 0, 0};
#pragma unroll
        for (int t = 0; t < 4; ++t) {
            float a = hread[r][t];
#pragma unroll
            for (int q = 0; q < 8; ++q) o[q] = fmaf(a, hnext[r][t * 128 + h0 + q], o[q]);
        }
        float* dst = hnew_out + (b0 + (r >> 3)) * HIDX + (r & 7) * 128 + h0;
        reinterpret_cast<float4*>(dst)[0] = make_float4(o[0], o[1], o[2], o[3]);
        reinterpret_cast<float4*>(dst)[1] = make_float4(o[4], o[5], o[6], o[7]);
    }
}

// ---------------- K3: comm attention + final select (unchanged, fp32) ----------------
__global__ __launch_bounds__(256) void k3_comm(
    const float* __restrict__ hx, const float* __restrict__ maskp,
    const float* __restrict__ Wq_c, const float* __restrict__ bq_c,
    const float* __restrict__ Wk_c, const float* __restrict__ bk_c,
    const float* __restrict__ Wv_c, const float* __restrict__ bv_c,
    const float* __restrict__ W_fc, const float* __restrict__ b_fc,
    const float* __restrict__ W_g, const float* __restrict__ b_g,
    float* hio)
{
    int b0 = blockIdx.x * 2;
    int tid = threadIdx.x;
    __shared__ float hT[128][16];
    __shared__ float qT[128][16];
    __shared__ float kT[128][16];
    __shared__ float vN[16][128];
    __shared__ float P[2][4][8][8];
    __shared__ float outT[128][16];
    __shared__ float fco[16][128];
    __shared__ float gco[16][128];

    {
#pragma unroll
        for (int q = 0; q < 2; ++q) {
            int idx = tid + q * 256;
            float4 hv = reinterpret_cast<const float4*>(hio + b0 * HIDX)[idx];
            int g = idx * 4;
            int r = g >> 7, i0 = g & 127;
            hT[i0 + 0][r] = hv.x; hT[i0 + 1][r] = hv.y; hT[i0 + 2][r] = hv.z; hT[i0 + 3][r] = hv.w;
        }
    }
    __syncthreads();
    {
        int jj = tid & 127;
        int r0 = (tid >> 7) * 8;
        float aq[8] = {0,0,0,0,0,0,0,0}, ak[8] = {0,0,0,0,0,0,0,0}, av[8] = {0,0,0,0,0,0,0,0};
        for (int i = 0; i < 128; ++i) {
            float wq = Wq_c[i * 128 + jj];
            float wk = Wk_c[i * 128 + jj];
            float wv = Wv_c[i * 128 + jj];
#pragma unroll
            for (int p = 0; p < 8; ++p) {
                float h = hT[i][r0 + p];
                aq[p] = fmaf(h, wq, aq[p]);
                ak[p] = fmaf(h, wk, ak[p]);
                av[p] = fmaf(h, wv, av[p]);
            }
        }
        float bq = bq_c[jj], bk = bk_c[jj], bv = bv_c[jj];
#pragma unroll
        for (int p = 0; p < 8; ++p) {
            qT[jj][r0 + p] = aq[p] + bq;
            kT[jj][r0 + p] = ak[p] + bk;
            vN[r0 + p][jj] = av[p] + bv;
        }
    }
    __syncthreads();
    if (tid < 64) {
        int bp = tid >> 5, ch = (tid >> 3) & 3, m = tid & 7;
        int r = bp * 8 + m;
        float s[8] = {0, 0, 0, 0, 0, 0, 0, 0};
        for (int d = 0; d < 32; ++d) {
            float qv = qT[ch * 32 + d][r];
#pragma unroll
            for (int n = 0; n < 8; ++n) s[n] = fmaf(qv, kT[ch * 32 + d][bp * 8 + n], s[n]);
        }
        const float scl = 0.17677669529663687f; // 1/sqrt(32)
        float mx = -3.0e38f;
        for (int n = 0; n < 8; ++n) { s[n] *= scl; mx = fmaxf(mx, s[n]); }
        float e[8], sum = 0.0f;
        for (int n = 0; n < 8; ++n) { e[n] = expf(s[n] - mx); sum += e[n]; }
        float inv = 1.0f / sum;
        for (int n = 0; n < 8; ++n) P[bp][ch][m][n] = e[n] * inv;
    }
    __syncthreads();
    {
        int r = tid >> 4, bp = r >> 3, m = r & 7;
        int c0 = (tid & 15) * 8, ch = c0 >> 5;
        float acc[8] = {0, 0, 0, 0, 0, 0, 0, 0};
#pragma unroll
        for (int n = 0; n < 8; ++n) {
            float p = P[bp][ch][m][n];
#pragma unroll
            for (int q = 0; q < 8; ++q) acc[q] = fmaf(p, vN[bp * 8 + n][c0 + q], acc[q]);
        }
#pragma unroll
        for (int q = 0; q < 8; ++q) outT[c0 + q][r] = acc[q];
    }
    __syncthreads();
    {
        int mat = tid >> 7, jj = tid & 127;
        const float* W = mat ? W_g : W_fc;
        float acc[16] = {0,0,0,0,0,0,0,0,0,0,0,0,0,0,0,0};
        for (int i = 0; i < 128; ++i) {
            float w = W[i * 128 + jj];
#pragma unroll
            for (int r = 0; r < 16; ++r) acc[r] = fmaf(outT[i][r], w, acc[r]);
        }
        if (mat == 0) {
            float bb = b_fc[jj];
            for (int r = 0; r < 16; ++r) fco[r][jj] = acc[r] + bb;
        } else {
            float bb = b_g[jj];
            for (int r = 0; r < 16; ++r) gco[r][jj] = acc[r] + bb;
        }
    }
    __syncthreads();
    {
        int r = tid >> 4, j0 = (tid & 15) * 8;
        int b = b0 + (r >> 3), m = r & 7;
        float mk = maskp[b * 8 + m];
        float res[8];
#pragma unroll
        for (int q = 0; q < 8; ++q) {
            int jj = j0 + q;
            float ao = sigm(gco[r][jj]) * tanhf(fco[r][jj]);
            float hn = hT[jj][r] + ao;
            float ho = hx[b * HIDX + m * 128 + jj];
            res[q] = mk * hn + (1.0f - mk) * ho;
        }
        float* dst = hio + b * HIDX + m * 128 + j0;
        reinterpret_cast<float4*>(dst)[0] = make_float4(res[0], res[1], res[2], res[3]);
        reinterpret_cast<float4*>(dst)[1] = make_float4(res[4], res[5], res[6], res[7]);
    }
}

// ---------------- launch ----------------
extern "C" void kernel_launch(void* const* d_in, const int* in_sizes, int n_in,
                              void* d_out, int out_size, void* d_ws, size_t ws_size,
                              hipStream_t stream)
{
    const float* inp     = (const float*)d_in[0];
    const float* hx      = (const float*)d_in[1];
    const float* Wq_in   = (const float*)d_in[3];
    const float* Wk_in   = (const float*)d_in[4];
    const float* Wv_in   = (const float*)d_in[5];
    const float* W_ih    = (const float*)d_in[6];
    const float* b_ih    = (const float*)d_in[7];
    const float* W_hh    = (const float*)d_in[8];
    const float* b_hh    = (const float*)d_in[9];
    const float* W_read  = (const float*)d_in[10];
    const float* W_write = (const float*)d_in[11];
    const float* Wq_c    = (const float*)d_in[12];
    const float* bq_c    = (const float*)d_in[13];
    const float* Wk_c    = (const float*)d_in[14];
    const float* bk_c    = (const float*)d_in[15];
    const float* Wv_c    = (const float*)d_in[16];
    const float* bv_c    = (const float*)d_in[17];
    const float* W_fc    = (const float*)d_in[18];
    const float* b_fc    = (const float*)d_in[19];
    const float* W_g     = (const float*)d_in[20];
    const float* b_g     = (const float*)d_in[21];

    float* out        = (float*)d_out;
    float* hx_out     = out;                 // B*1024
    float* mask_full  = out + 4194304;       // B*1024 (also temp home of inp_use)
    float* block_mask = out + 8388608;       // B*8
    float* temp_att   = out + 8421376;       // B*8*4

    float* ws    = (float*)d_ws;
    float* Wvm   = ws;                            // 16384 f
    float* maskp = ws + 16384;                    // 32768 f
    unsigned short* Bpk = (unsigned short*)(ws + 16384 + 32768); // 393216 bf16
    // total ws: ~1.0 MB

    k0_prep<<<1600, 256, 0, stream>>>(Wv_in, W_ih, W_hh, Wvm, Bpk);
    k1_input_attn<<<NB, 256, 0, stream>>>(inp, hx, Wq_in, Wk_in, Wvm,
                                          mask_full /*inp_use*/, maskp, block_mask);
    k2_gru<<<NB / 2, 256, 0, stream>>>(mask_full /*inp_use -> mask_full*/, hx,
                                       Bpk, b_ih, b_hh, W_read, W_write,
                                       maskp, hx_out /*hnew*/, temp_att);
    k3_comm<<<NB / 2, 256, 0, stream>>>(hx, maskp, Wq_c, bq_c, Wk_c, bk_c,
                                        Wv_c, bv_c, W_fc, b_fc, W_g, b_g, hx_out);
}

// Round 12
// 397.745 us; speedup vs baseline: 2.1369x; 1.1863x over previous
//
#include <hip/hip_runtime.h>
#include <cmath>

// ---------------- constants ----------------
// B=4096, M=8, HSS=128, HID=1024, T=4, CH=4, CDK=32, CDV=32
#define NB 4096
#define HIDX 1024

// d_out layout (floats): hx_out[4194304] | mask_full[4194304] | block_mask[32768] | temp_att[131072]

__device__ __forceinline__ float sigm(float x) { return 1.0f / (1.0f + expf(-x)); }

// round-to-nearest-even fp32 -> bf16 bits
__device__ __forceinline__ unsigned short f2bf(float f) {
    unsigned u = __float_as_uint(f);
    unsigned r = (u + 0x7FFFu + ((u >> 16) & 1u)) >> 16;
    return (unsigned short)r;
}

typedef __attribute__((ext_vector_type(8))) short short8v;  // 8 bf16
typedef __attribute__((ext_vector_type(4))) float f32x4;

// ---------------- K0: weight prep ----------------
// Wvm[i][d] = mean over 4 heads of Wv_in[i][h*128+d]  (128x128 fp32)
// Bpk  (GRU): block = ((t*4+ks)*6+g)*8 + jt ; within: lane l, elem e:
//   k = ks*32 + 4*(l>>4) + (e&3) + (e&4?16:0); n = jt*16 + (l&15)
//   g<3 -> W_ih[t][g*128+n][k] ; else W_hh[t][(g-3)*128+n][k]
// Bqkv (comm qkv): block = ks*24 + jt (jt 0..23); mat=jt/8; n=(jt%8)*16+(l&15)
//   mat0 Wq_c[k*128+n], mat1 Wk_c[k*128+n], mat2 Wv_c[k*128+n]   (W is [in][out])
// Bfg  (fc/gate): block = ks*16 + jt (jt 0..15); mat=jt/8;
//   mat0 W_fc[k*128+n], mat1 W_g[k*128+n]
__global__ __launch_bounds__(256) void k0_prep(
    const float* __restrict__ Wv_in, const float* __restrict__ W_ih,
    const float* __restrict__ W_hh,
    const float* __restrict__ Wq_c, const float* __restrict__ Wk_c,
    const float* __restrict__ Wv_c, const float* __restrict__ W_fc,
    const float* __restrict__ W_g,
    float* __restrict__ Wvm, unsigned short* __restrict__ Bpk,
    unsigned short* __restrict__ Bqkv, unsigned short* __restrict__ Bfg)
{
    int idx = blockIdx.x * 256 + threadIdx.x;
    if (idx < 16384) {
        int i = idx >> 7, d = idx & 127;
        const float* p = Wv_in + i * 512 + d;
        Wvm[idx] = 0.25f * (p[0] + p[128] + p[256] + p[384]);
    } else if (idx < 409600) {
        int o = idx - 16384;
        int e = o & 7, l = (o >> 3) & 63, blk = o >> 9;
        int jt = blk & 7, gq = blk >> 3;
        int g = gq % 6, q2 = gq / 6;
        int ks = q2 & 3, t = q2 >> 2;
        int k = ks * 32 + 4 * (l >> 4) + (e & 3) + ((e & 4) ? 16 : 0);
        int n = jt * 16 + (l & 15);
        float v = (g < 3) ? W_ih[(t * 384 + g * 128 + n) * 128 + k]
                          : W_hh[(t * 384 + (g - 3) * 128 + n) * 128 + k];
        Bpk[o] = f2bf(v);
    } else if (idx < 458752) {
        int o = idx - 409600;                // 0..49151
        int e = o & 7, l = (o >> 3) & 63, blk = o >> 9;   // blk 0..95
        int jt = blk % 24, ks = blk / 24;
        int k = ks * 32 + 4 * (l >> 4) + (e & 3) + ((e & 4) ? 16 : 0);
        int mat = jt >> 3;
        int n = ((jt & 7) << 4) + (l & 15);
        float v = (mat == 0) ? Wq_c[k * 128 + n]
                : (mat == 1) ? Wk_c[k * 128 + n]
                             : Wv_c[k * 128 + n];
        Bqkv[o] = f2bf(v);
    } else if (idx < 491520) {
        int o = idx - 458752;                // 0..32767
        int e = o & 7, l = (o >> 3) & 63, blk = o >> 9;   // blk 0..63
        int jt = blk & 15, ks = blk >> 4;
        int k = ks * 32 + 4 * (l >> 4) + (e & 3) + ((e & 4) ? 16 : 0);
        int mat = jt >> 3;
        int n = ((jt & 7) << 4) + (l & 15);
        float v = mat ? W_g[k * 128 + n] : W_fc[k * 128 + n];
        Bfg[o] = f2bf(v);
    }
}

// ---------------- K1: input attention (unchanged, fp32 — top-4 needs fp32 scores) ----------------
__global__ __launch_bounds__(256) void k1_input_attn(
    const float* __restrict__ inp, const float* __restrict__ hx,
    const float* __restrict__ Wq, const float* __restrict__ Wk,
    const float* __restrict__ Wvm,
    float* iu /*inp_use out (aliases mask_full slot)*/,
    float* __restrict__ maskp, float* __restrict__ block_mask)
{
    int b = blockIdx.x;
    int tid = threadIdx.x;
    __shared__ float hT[128][8];
    __shared__ float xT[128][8];
    __shared__ float QT[256][8];
    __shared__ float KT[256][8];
    __shared__ float V[8][128];
    __shared__ float S[8][8];
    __shared__ float P[8][9];
    __shared__ float nnull[8];
    __shared__ float maskS[8];

    {
        float4 hv = reinterpret_cast<const float4*>(hx + b * HIDX)[tid];
        float4 xv = reinterpret_cast<const float4*>(inp + b * HIDX)[tid];
        int g = tid * 4;
        int m = g >> 7, i0 = g & 127;
        hT[i0 + 0][m] = hv.x; hT[i0 + 1][m] = hv.y; hT[i0 + 2][m] = hv.z; hT[i0 + 3][m] = hv.w;
        xT[i0 + 0][m] = xv.x; xT[i0 + 1][m] = xv.y; xT[i0 + 2][m] = xv.z; xT[i0 + 3][m] = xv.w;
    }
    __syncthreads();
    {
        int j = tid;
        float aq[8] = {0, 0, 0, 0, 0, 0, 0, 0};
        float ak[8] = {0, 0, 0, 0, 0, 0, 0, 0};
        for (int i = 0; i < 128; ++i) {
            float wq = Wq[i * 256 + j];
            float wk = Wk[i * 256 + j];
#pragma unroll
            for (int m = 0; m < 8; ++m) {
                aq[m] = fmaf(hT[i][m], wq, aq[m]);
                ak[m] = fmaf(xT[i][m], wk, ak[m]);
            }
        }
#pragma unroll
        for (int m = 0; m < 8; ++m) { QT[j][m] = aq[m]; KT[j][m] = ak[m]; }
    }
    {
        int d = tid & 127;
        int n0 = (tid >> 7) * 4;
        float av[4] = {0, 0, 0, 0};
        for (int i = 0; i < 128; ++i) {
            float w = Wvm[i * 128 + d];
#pragma unroll
            for (int p = 0; p < 4; ++p) av[p] = fmaf(xT[i][n0 + p], w, av[p]);
        }
#pragma unroll
        for (int p = 0; p < 4; ++p) V[n0 + p][d] = av[p];
    }
    __syncthreads();
    if (tid < 64) {
        int m = tid >> 3, n = tid & 7;
        float s = 0.0f;
        for (int c = 0; c < 256; ++c) s = fmaf(QT[c][m], KT[c][n], s);
        S[m][n] = s * (1.0f / 32.0f);
    }
    __syncthreads();
    if (tid < 8) {
        int m = tid;
        float mx = 0.0f;
        for (int n = 0; n < 8; ++n) mx = fmaxf(mx, S[m][n]);
        float en = expf(0.0f - mx);
        float sum = en;
        float e[8];
        for (int n = 0; n < 8; ++n) { e[n] = expf(S[m][n] - mx); sum += e[n]; }
        float inv = 1.0f / sum;
        for (int n = 0; n < 8; ++n) P[m][n] = e[n] * inv;
        nnull[m] = 1.0f - en * inv;
    }
    __syncthreads();
    if (tid == 0) {
        unsigned sel = 0;
        for (int s = 0; s < 4; ++s) {
            int best = 0; float bv = -3.0e38f;
            for (int m = 0; m < 8; ++m)
                if (!(sel & (1u << m)) && nnull[m] > bv) { bv = nnull[m]; best = m; }
            sel |= 1u << best;
        }
        for (int m = 0; m < 8; ++m) maskS[m] = (sel & (1u << m)) ? 1.0f : 0.0f;
    }
    __syncthreads();
    {
        int m = tid >> 5;
        int d0 = (tid & 31) * 4;
        float acc[4] = {0, 0, 0, 0};
#pragma unroll
        for (int n = 0; n < 8; ++n) {
            float p = P[m][n];
#pragma unroll
            for (int q = 0; q < 4; ++q) acc[q] = fmaf(p, V[n][d0 + q], acc[q]);
        }
        float mk = maskS[m];
        reinterpret_cast<float4*>(iu + b * HIDX + m * 128 + d0)[0] =
            make_float4(acc[0] * mk, acc[1] * mk, acc[2] * mk, acc[3] * mk);
    }
    if (tid < 8) {
        maskp[b * 8 + tid] = maskS[tid];
        block_mask[b * 8 + tid] = maskS[tid];
    }
}

// ---------------- K2: shared block GRU via MFMA (unchanged from passing round 8) ----------------
__global__ __launch_bounds__(256) void k2_gru(
    float* iu /*in: inp_use, out: mask_full (same memory)*/,
    const float* __restrict__ hx,
    const unsigned short* __restrict__ Bpk,
    const float* __restrict__ b_ih, const float* __restrict__ b_hh,
    const float* __restrict__ W_read, const float* __restrict__ W_write,
    const float* __restrict__ maskp,
    float* __restrict__ hnew_out, float* __restrict__ temp_att)
{
    int b0 = blockIdx.x * 2;
    int tid = threadIdx.x;
    __shared__ float hs[16][132];              // fp32 H rows, padded (bank spread)
    __shared__ unsigned short Af[2][4][64][8]; // A-frags [mat x|h][ks][lane][8 bf16]
    __shared__ float hnext[16][516];
    __shared__ float hread[16][16];
    // wkey aliases Af (dead after GEMM): 4 KB <= 8 KB
    float (*wkey)[4][16] = reinterpret_cast<float (*)[4][16]>(&Af[0][0][0][0]);

    // ---- stage: hs fp32, A-fragments bf16, emit mask_full in place ----
#pragma unroll
    for (int it = 0; it < 2; ++it) {
        int idx = tid + it * 256;              // 0..511 float4 slots
        int r = idx >> 5, q = idx & 31;        // row, float4-index (k0 = 4q)
        float4 xv = reinterpret_cast<const float4*>(iu + b0 * HIDX)[idx];
        float4 hv = reinterpret_cast<const float4*>(hx + b0 * HIDX)[idx];
        hs[r][4 * q + 0] = hv.x; hs[r][4 * q + 1] = hv.y;
        hs[r][4 * q + 2] = hv.z; hs[r][4 * q + 3] = hv.w;
        int ks = q >> 3, rem = q & 7, hi = rem >> 2, p = rem & 3;
        int l = p * 16 + r;
        *reinterpret_cast<ushort4*>(&Af[0][ks][l][hi * 4]) =
            make_ushort4(f2bf(xv.x), f2bf(xv.y), f2bf(xv.z), f2bf(xv.w));
        *reinterpret_cast<ushort4*>(&Af[1][ks][l][hi * 4]) =
            make_ushort4(f2bf(hv.x), f2bf(hv.y), f2bf(hv.z), f2bf(hv.w));
        float mkv = maskp[b0 * 8 + r];
        reinterpret_cast<float4*>(iu + b0 * HIDX)[idx] = make_float4(mkv, mkv, mkv, mkv);
    }
    __syncthreads();

    int lane = tid & 63, wid = tid >> 6;
    short8v ax[4], ah[4];
#pragma unroll
    for (int ks = 0; ks < 4; ++ks) {
        ax[ks] = *reinterpret_cast<const short8v*>(&Af[0][ks][lane][0]);
        ah[ks] = *reinterpret_cast<const short8v*>(&Af[1][ks][lane][0]);
    }
    int jl = wid * 32 + (lane & 15);   // j for jt=0 (add 16 for jt=1)
    int rbase = (lane >> 4) * 4;       // C/D: row = rbase + reg, col = lane&15

    for (int t = 0; t < 4; ++t) {
        f32x4 acc[2][6];
#pragma unroll
        for (int jt = 0; jt < 2; ++jt)
#pragma unroll
            for (int g = 0; g < 6; ++g)
                acc[jt][g] = (f32x4){0.f, 0.f, 0.f, 0.f};
#pragma unroll
        for (int ks = 0; ks < 4; ++ks) {
            const unsigned short* pb =
                Bpk + (size_t)((((t * 4 + ks) * 6) * 8 + wid * 2) * 512 + lane * 8);
#pragma unroll
            for (int g = 0; g < 6; ++g) {
                short8v bv0 = *reinterpret_cast<const short8v*>(pb + g * 4096);
                short8v bv1 = *reinterpret_cast<const short8v*>(pb + g * 4096 + 512);
                short8v a = (g < 3) ? ax[ks] : ah[ks];
                acc[0][g] = __builtin_amdgcn_mfma_f32_16x16x32_bf16(a, bv0, acc[0][g], 0, 0, 0);
                acc[1][g] = __builtin_amdgcn_mfma_f32_16x16x32_bf16(a, bv1, acc[1][g], 0, 0, 0);
            }
        }
#pragma unroll
        for (int jt = 0; jt < 2; ++jt) {
            int j = jl + jt * 16;
            float bir = b_ih[t * 384 + j],       bhr = b_hh[t * 384 + j];
            float biz = b_ih[t * 384 + 128 + j], bhz = b_hh[t * 384 + 128 + j];
            float bin = b_ih[t * 384 + 256 + j], bhn = b_hh[t * 384 + 256 + j];
#pragma unroll
            for (int rg = 0; rg < 4; ++rg) {
                int row = rbase + rg;
                float ir  = acc[jt][0][rg] + bir;
                float iz  = acc[jt][1][rg] + biz;
                float inn = acc[jt][2][rg] + bin;
                float hr  = acc[jt][3][rg] + bhr;
                float hz  = acc[jt][4][rg] + bhz;
                float hn  = acc[jt][5][rg] + bhn;
                float rr = sigm(ir + hr);
                float zz = sigm(iz + hz);
                float nn = tanhf(inn + rr * hn);
                hnext[row][t * 128 + j] = (1.0f - zz) * nn + zz * hs[row][j];
            }
        }
    }
    __syncthreads();

    { // h_read (16x16) and w_key (16x4x16)
        int r = tid >> 4, k = tid & 15;
        float acc = 0.0f;
        for (int h2 = 0; h2 < 128; ++h2) acc = fmaf(hs[r][h2], W_read[h2 * 16 + k], acc);
        hread[r][k] = acc;
        for (int t = 0; t < 4; ++t) {
            float a2v = 0.0f;
            for (int h2 = 0; h2 < 128; ++h2)
                a2v = fmaf(hnext[r][t * 128 + h2], W_write[(t * 128 + h2) * 16 + k], a2v);
            wkey[r][t][k] = a2v;
        }
    }
    __syncthreads();
    if (tid < 16) { // template softmax; att into hread[r][0..3]
        int r = tid;
        float lg[4];
        for (int t = 0; t < 4; ++t) {
            float s = 0.0f;
            for (int k = 0; k < 16; ++k) s = fmaf(hread[r][k], wkey[r][t][k], s);
            lg[t] = s * 0.25f;
        }
        float mx = fmaxf(fmaxf(lg[0], lg[1]), fmaxf(lg[2], lg[3]));
        float e[4], sum = 0.0f;
        for (int t = 0; t < 4; ++t) { e[t] = expf(lg[t] - mx); sum += e[t]; }
        float inv = 1.0f / sum;
        float att[4];
        for (int t = 0; t < 4; ++t) att[t] = e[t] * inv;
        for (int t = 0; t < 4; ++t) {
            hread[r][t] = att[t];
            temp_att[(b0 * 8 + r) * 4 + t] = att[t];
        }
    }
    __syncthreads();
    { // hnew = sum_t att[t] * hnext[t]
        int r = tid >> 4;
        int h0 = (tid & 15) * 8;
        float o[8] = {0, 0, 0, 0, 0, 0, 0, 0};
#pragma unroll
        for (int t = 0; t < 4; ++t) {
            float a = hread[r][t];
#pragma unroll
            for (int q = 0; q < 8; ++q) o[q] = fmaf(a, hnext[r][t * 128 + h0 + q], o[q]);
        }
        float* dst = hnew_out + (b0 + (r >> 3)) * HIDX + (r & 7) * 128 + h0;
        reinterpret_cast<float4*>(dst)[0] = make_float4(o[0], o[1], o[2], o[3]);
        reinterpret_cast<float4*>(dst)[1] = make_float4(o[4], o[5], o[6], o[7]);
    }
}

// ---------------- K3: comm attention + final select via MFMA ----------------
// 2 batch elements (16 rows) per WG, 256 threads = 4 waves, 3 WGs/CU (40.4 KB LDS).
// qkv + fc/gate GEMMs on matrix cores (k2-verified fragment mapping);
// scores/softmax/PV/final stay fp32 (all smooth — no discrete decisions in k3).
__global__ __launch_bounds__(256) void k3_comm(
    const float* __restrict__ hx, const float* __restrict__ maskp,
    const unsigned short* __restrict__ Bqkv, const unsigned short* __restrict__ Bfg,
    const float* __restrict__ bq_c, const float* __restrict__ bk_c,
    const float* __restrict__ bv_c, const float* __restrict__ b_fc,
    const float* __restrict__ b_g,
    float* hio)
{
    int b0 = blockIdx.x * 2;
    int tid = threadIdx.x;
    __shared__ float hs[16][132];              // hnew fp32 natural [row][c]
    __shared__ unsigned short Af[4][64][8];    // A-frags: h (qkv), then out (fc/gate)
    __shared__ float qT[128][17];              // [c][row]; later aliased by fco[16][132]
    __shared__ float kT[128][17];              // [c][row]; later aliased by gco[16][132]
    __shared__ float vN[16][132];              // [row][c]
    __shared__ float P[2][4][8][8];            // [b'][ch][m][n]
    float (*fco)[132] = reinterpret_cast<float (*)[132]>(&qT[0][0]);
    float (*gco)[132] = reinterpret_cast<float (*)[132]>(&kT[0][0]);

    // ---- stage hnew: fp32 rows + bf16 A-frags ----
#pragma unroll
    for (int it = 0; it < 2; ++it) {
        int idx = tid + it * 256;
        int r = idx >> 5, q = idx & 31;
        float4 hv = reinterpret_cast<const float4*>(hio + b0 * HIDX)[idx];
        hs[r][4 * q + 0] = hv.x; hs[r][4 * q + 1] = hv.y;
        hs[r][4 * q + 2] = hv.z; hs[r][4 * q + 3] = hv.w;
        int ks = q >> 3, rem = q & 7, hi = rem >> 2, p = rem & 3;
        int l = p * 16 + r;
        *reinterpret_cast<ushort4*>(&Af[ks][l][hi * 4]) =
            make_ushort4(f2bf(hv.x), f2bf(hv.y), f2bf(hv.z), f2bf(hv.w));
    }
    __syncthreads();

    int lane = tid & 63, wid = tid >> 6;
    int rbase = (lane >> 4) * 4;
    int cl = lane & 15;

    { // ---- QKV GEMM: 24 j-tiles over [Wq|Wk|Wv], wave w does jt = w+4u ----
        short8v ah[4];
#pragma unroll
        for (int ks = 0; ks < 4; ++ks)
            ah[ks] = *reinterpret_cast<const short8v*>(&Af[ks][lane][0]);
#pragma unroll
        for (int u = 0; u < 6; ++u) {
            int jt = wid + 4 * u;
            f32x4 acc = (f32x4){0.f, 0.f, 0.f, 0.f};
#pragma unroll
            for (int ks = 0; ks < 4; ++ks) {
                short8v bv = *reinterpret_cast<const short8v*>(
                    Bqkv + (size_t)(ks * 24 + jt) * 512 + lane * 8);
                acc = __builtin_amdgcn_mfma_f32_16x16x32_bf16(ah[ks], bv, acc, 0, 0, 0);
            }
            int mat = jt >> 3;
            int n = ((jt & 7) << 4) + cl;
            if (mat == 0) {
                float bb = bq_c[n];
#pragma unroll
                for (int rg = 0; rg < 4; ++rg) qT[n][rbase + rg] = acc[rg] + bb;
            } else if (mat == 1) {
                float bb = bk_c[n];
#pragma unroll
                for (int rg = 0; rg < 4; ++rg) kT[n][rbase + rg] = acc[rg] + bb;
            } else {
                float bb = bv_c[n];
#pragma unroll
                for (int rg = 0; rg < 4; ++rg) vN[rbase + rg][n] = acc[rg] + bb;
            }
        }
    }
    __syncthreads();

    if (tid < 64) { // ---- per-head scores + softmax (fp32) ----
        int bp = tid >> 5, ch = (tid >> 3) & 3, m = tid & 7;
        int r = bp * 8 + m;
        float s[8] = {0, 0, 0, 0, 0, 0, 0, 0};
        for (int d = 0; d < 32; ++d) {
            float qv = qT[ch * 32 + d][r];
#pragma unroll
            for (int n = 0; n < 8; ++n) s[n] = fmaf(qv, kT[ch * 32 + d][bp * 8 + n], s[n]);
        }
        const float scl = 0.17677669529663687f; // 1/sqrt(32)
        float mx = -3.0e38f;
        for (int n = 0; n < 8; ++n) { s[n] *= scl; mx = fmaxf(mx, s[n]); }
        float e[8], sum = 0.0f;
        for (int n = 0; n < 8; ++n) { e[n] = expf(s[n] - mx); sum += e[n]; }
        float inv = 1.0f / sum;
        for (int n = 0; n < 8; ++n) P[bp][ch][m][n] = e[n] * inv;
    }
    __syncthreads();

    { // ---- PV (fp32) -> write `out` rows directly as bf16 A-frags into Af ----
        int r = tid >> 4, bp = r >> 3, m = r & 7;
        int c0 = (tid & 15) * 8, ch = c0 >> 5;
        float acc[8] = {0, 0, 0, 0, 0, 0, 0, 0};
#pragma unroll
        for (int n = 0; n < 8; ++n) {
            float p = P[bp][ch][m][n];
#pragma unroll
            for (int q = 0; q < 8; ++q) acc[q] = fmaf(p, vN[bp * 8 + n][c0 + q], acc[q]);
        }
        int q0 = (tid & 15) * 2;
#pragma unroll
        for (int dq = 0; dq < 2; ++dq) {
            int qq = q0 + dq;
            int ks = qq >> 3, rem = qq & 7, hi = rem >> 2, p2 = rem & 3;
            int l = p2 * 16 + r;
            *reinterpret_cast<ushort4*>(&Af[ks][l][hi * 4]) =
                make_ushort4(f2bf(acc[dq * 4 + 0]), f2bf(acc[dq * 4 + 1]),
                             f2bf(acc[dq * 4 + 2]), f2bf(acc[dq * 4 + 3]));
        }
    }
    __syncthreads();

    { // ---- fc & gate GEMM: 16 j-tiles over [W_fc|W_g]; fco/gco alias qT/kT ----
        short8v ao2[4];
#pragma unroll
        for (int ks = 0; ks < 4; ++ks)
            ao2[ks] = *reinterpret_cast<const short8v*>(&Af[ks][lane][0]);
#pragma unroll
        for (int u = 0; u < 4; ++u) {
            int jt = wid + 4 * u;
            f32x4 acc = (f32x4){0.f, 0.f, 0.f, 0.f};
#pragma unroll
            for (int ks = 0; ks < 4; ++ks) {
                short8v bv = *reinterpret_cast<const short8v*>(
                    Bfg + (size_t)(ks * 16 + jt) * 512 + lane * 8);
                acc = __builtin_amdgcn_mfma_f32_16x16x32_bf16(ao2[ks], bv, acc, 0, 0, 0);
            }
            int mat = jt >> 3;
            int n = ((jt & 7) << 4) + cl;
            if (mat == 0) {
                float bb = b_fc[n];
#pragma unroll
                for (int rg = 0; rg < 4; ++rg) fco[rbase + rg][n] = acc[rg] + bb;
            } else {
                float bb = b_g[n];
#pragma unroll
                for (int rg = 0; rg < 4; ++rg) gco[rbase + rg][n] = acc[rg] + bb;
            }
        }
    }
    __syncthreads();

    { // ---- final: att_out = sigm(gate)*tanh(fc); hx_out = mask ? hnew+ao : hx ----
        int r = tid >> 4, j0 = (tid & 15) * 8;
        int b = b0 + (r >> 3), m = r & 7;
        float mk = maskp[b * 8 + m];
        float res[8];
#pragma unroll
        for (int q = 0; q < 8; ++q) {
            int jj = j0 + q;
            float ao = sigm(gco[r][jj]) * tanhf(fco[r][jj]);
            float hn = hs[r][jj] + ao;
            float ho = hx[b * HIDX + m * 128 + jj];
            res[q] = mk * hn + (1.0f - mk) * ho;
        }
        float* dst = hio + b * HIDX + m * 128 + j0;
        reinterpret_cast<float4*>(dst)[0] = make_float4(res[0], res[1], res[2], res[3]);
        reinterpret_cast<float4*>(dst)[1] = make_float4(res[4], res[5], res[6], res[7]);
    }
}

// ---------------- launch ----------------
extern "C" void kernel_launch(void* const* d_in, const int* in_sizes, int n_in,
                              void* d_out, int out_size, void* d_ws, size_t ws_size,
                              hipStream_t stream)
{
    const float* inp     = (const float*)d_in[0];
    const float* hx      = (const float*)d_in[1];
    const float* Wq_in   = (const float*)d_in[3];
    const float* Wk_in   = (const float*)d_in[4];
    const float* Wv_in   = (const float*)d_in[5];
    const float* W_ih    = (const float*)d_in[6];
    const float* b_ih    = (const float*)d_in[7];
    const float* W_hh    = (const float*)d_in[8];
    const float* b_hh    = (const float*)d_in[9];
    const float* W_read  = (const float*)d_in[10];
    const float* W_write = (const float*)d_in[11];
    const float* Wq_c    = (const float*)d_in[12];
    const float* bq_c    = (const float*)d_in[13];
    const float* Wk_c    = (const float*)d_in[14];
    const float* bk_c    = (const float*)d_in[15];
    const float* Wv_c    = (const float*)d_in[16];
    const float* bv_c    = (const float*)d_in[17];
    const float* W_fc    = (const float*)d_in[18];
    const float* b_fc    = (const float*)d_in[19];
    const float* W_g     = (const float*)d_in[20];
    const float* b_g     = (const float*)d_in[21];

    float* out        = (float*)d_out;
    float* hx_out     = out;                 // B*1024
    float* mask_full  = out + 4194304;       // B*1024 (also temp home of inp_use)
    float* block_mask = out + 8388608;       // B*8
    float* temp_att   = out + 8421376;       // B*8*4

    float* ws    = (float*)d_ws;
    float* Wvm   = ws;                            // 16384 f
    float* maskp = ws + 16384;                    // 32768 f
    unsigned short* Bpk  = (unsigned short*)(ws + 49152);  // 393216 us
    unsigned short* Bqkv = Bpk + 393216;                   // 49152 us
    unsigned short* Bfg  = Bqkv + 49152;                   // 32768 us
    // total ws: ~1.15 MB

    k0_prep<<<1920, 256, 0, stream>>>(Wv_in, W_ih, W_hh, Wq_c, Wk_c, Wv_c,
                                      W_fc, W_g, Wvm, Bpk, Bqkv, Bfg);
    k1_input_attn<<<NB, 256, 0, stream>>>(inp, hx, Wq_in, Wk_in, Wvm,
                                          mask_full /*inp_use*/, maskp, block_mask);
    k2_gru<<<NB / 2, 256, 0, stream>>>(mask_full /*inp_use -> mask_full*/, hx,
                                       Bpk, b_ih, b_hh, W_read, W_write,
                                       maskp, hx_out /*hnew*/, temp_att);
    k3_comm<<<NB / 2, 256, 0, stream>>>(hx, maskp, Bqkv, Bfg,
                                        bq_c, bk_c, bv_c, b_fc, b_g, hx_out);
}

// Round 13
// 344.092 us; speedup vs baseline: 2.4701x; 1.1559x over previous
//
#include <hip/hip_runtime.h>
#include <cmath>

// ---------------- constants ----------------
// B=4096, M=8, HSS=128, HID=1024, T=4, CH=4, CDK=32, CDV=32
#define NB 4096
#define HIDX 1024

// d_out layout (floats): hx_out[4194304] | mask_full[4194304] | block_mask[32768] | temp_att[131072]

__device__ __forceinline__ float sigm(float x) { return 1.0f / (1.0f + expf(-x)); }

// round-to-nearest-even fp32 -> bf16 bits
__device__ __forceinline__ unsigned short f2bf(float f) {
    unsigned u = __float_as_uint(f);
    unsigned r = (u + 0x7FFFu + ((u >> 16) & 1u)) >> 16;
    return (unsigned short)r;
}

typedef __attribute__((ext_vector_type(8))) short short8v;  // 8 bf16
typedef __attribute__((ext_vector_type(4))) float f32x4;

// ---------------- K0: weight prep ----------------
// Wvm[i][d] = mean over 4 heads of Wv_in[i][h*128+d]  (128x128 fp32)
// Shared k-perm for all B-fragments: k = ks*32 + 4*(l>>4) + (e&3) + (e&4?16:0)
// Bpk  (GRU): block = ((t*4+ks)*6+g)*8 + jt ; n = jt*16 + (l&15)
// Bqkv (comm qkv): block = ks*24 + jt (jt 0..23); mat=jt/8; n=(jt%8)*16+(l&15)
// Bfg  (fc/gate): block = ks*16 + jt (jt 0..15); mat=jt/8
// Brw  (read/write keys): blocks 0..3 = W_read[k*16+n] (ks=blk);
//      blocks 4..19 = W_write[t][k][n], t=(blk-4)>>2, ks=blk&3; n=l&15
__global__ __launch_bounds__(256) void k0_prep(
    const float* __restrict__ Wv_in, const float* __restrict__ W_ih,
    const float* __restrict__ W_hh,
    const float* __restrict__ Wq_c, const float* __restrict__ Wk_c,
    const float* __restrict__ Wv_c, const float* __restrict__ W_fc,
    const float* __restrict__ W_g,
    const float* __restrict__ W_read, const float* __restrict__ W_write,
    float* __restrict__ Wvm, unsigned short* __restrict__ Bpk,
    unsigned short* __restrict__ Bqkv, unsigned short* __restrict__ Bfg,
    unsigned short* __restrict__ Brw)
{
    int idx = blockIdx.x * 256 + threadIdx.x;
    if (idx < 16384) {
        int i = idx >> 7, d = idx & 127;
        const float* p = Wv_in + i * 512 + d;
        Wvm[idx] = 0.25f * (p[0] + p[128] + p[256] + p[384]);
    } else if (idx < 409600) {
        int o = idx - 16384;
        int e = o & 7, l = (o >> 3) & 63, blk = o >> 9;
        int jt = blk & 7, gq = blk >> 3;
        int g = gq % 6, q2 = gq / 6;
        int ks = q2 & 3, t = q2 >> 2;
        int k = ks * 32 + 4 * (l >> 4) + (e & 3) + ((e & 4) ? 16 : 0);
        int n = jt * 16 + (l & 15);
        float v = (g < 3) ? W_ih[(t * 384 + g * 128 + n) * 128 + k]
                          : W_hh[(t * 384 + (g - 3) * 128 + n) * 128 + k];
        Bpk[o] = f2bf(v);
    } else if (idx < 458752) {
        int o = idx - 409600;                // 0..49151
        int e = o & 7, l = (o >> 3) & 63, blk = o >> 9;   // blk 0..95
        int jt = blk % 24, ks = blk / 24;
        int k = ks * 32 + 4 * (l >> 4) + (e & 3) + ((e & 4) ? 16 : 0);
        int mat = jt >> 3;
        int n = ((jt & 7) << 4) + (l & 15);
        float v = (mat == 0) ? Wq_c[k * 128 + n]
                : (mat == 1) ? Wk_c[k * 128 + n]
                             : Wv_c[k * 128 + n];
        Bqkv[o] = f2bf(v);
    } else if (idx < 491520) {
        int o = idx - 458752;                // 0..32767
        int e = o & 7, l = (o >> 3) & 63, blk = o >> 9;   // blk 0..63
        int jt = blk & 15, ks = blk >> 4;
        int k = ks * 32 + 4 * (l >> 4) + (e & 3) + ((e & 4) ? 16 : 0);
        int mat = jt >> 3;
        int n = ((jt & 7) << 4) + (l & 15);
        float v = mat ? W_g[k * 128 + n] : W_fc[k * 128 + n];
        Bfg[o] = f2bf(v);
    } else if (idx < 501760) {
        int o = idx - 491520;                // 0..10239
        int e = o & 7, l = (o >> 3) & 63, blk = o >> 9;   // blk 0..19
        int k = (blk & 3) * 32 + 4 * (l >> 4) + (e & 3) + ((e & 4) ? 16 : 0);
        int n = l & 15;
        float v;
        if (blk < 4) v = W_read[k * 16 + n];
        else { int t = (blk - 4) >> 2; v = W_write[(t * 128 + k) * 16 + n]; }
        Brw[o] = f2bf(v);
    }
}

// ---------------- K1: input attention (unchanged, fp32 — top-4 needs fp32 scores) ----------------
__global__ __launch_bounds__(256) void k1_input_attn(
    const float* __restrict__ inp, const float* __restrict__ hx,
    const float* __restrict__ Wq, const float* __restrict__ Wk,
    const float* __restrict__ Wvm,
    float* iu /*inp_use out (aliases mask_full slot)*/,
    float* __restrict__ maskp, float* __restrict__ block_mask)
{
    int b = blockIdx.x;
    int tid = threadIdx.x;
    __shared__ float hT[128][8];
    __shared__ float xT[128][8];
    __shared__ float QT[256][8];
    __shared__ float KT[256][8];
    __shared__ float V[8][128];
    __shared__ float S[8][8];
    __shared__ float P[8][9];
    __shared__ float nnull[8];
    __shared__ float maskS[8];

    {
        float4 hv = reinterpret_cast<const float4*>(hx + b * HIDX)[tid];
        float4 xv = reinterpret_cast<const float4*>(inp + b * HIDX)[tid];
        int g = tid * 4;
        int m = g >> 7, i0 = g & 127;
        hT[i0 + 0][m] = hv.x; hT[i0 + 1][m] = hv.y; hT[i0 + 2][m] = hv.z; hT[i0 + 3][m] = hv.w;
        xT[i0 + 0][m] = xv.x; xT[i0 + 1][m] = xv.y; xT[i0 + 2][m] = xv.z; xT[i0 + 3][m] = xv.w;
    }
    __syncthreads();
    {
        int j = tid;
        float aq[8] = {0, 0, 0, 0, 0, 0, 0, 0};
        float ak[8] = {0, 0, 0, 0, 0, 0, 0, 0};
        for (int i = 0; i < 128; ++i) {
            float wq = Wq[i * 256 + j];
            float wk = Wk[i * 256 + j];
#pragma unroll
            for (int m = 0; m < 8; ++m) {
                aq[m] = fmaf(hT[i][m], wq, aq[m]);
                ak[m] = fmaf(xT[i][m], wk, ak[m]);
            }
        }
#pragma unroll
        for (int m = 0; m < 8; ++m) { QT[j][m] = aq[m]; KT[j][m] = ak[m]; }
    }
    {
        int d = tid & 127;
        int n0 = (tid >> 7) * 4;
        float av[4] = {0, 0, 0, 0};
        for (int i = 0; i < 128; ++i) {
            float w = Wvm[i * 128 + d];
#pragma unroll
            for (int p = 0; p < 4; ++p) av[p] = fmaf(xT[i][n0 + p], w, av[p]);
        }
#pragma unroll
        for (int p = 0; p < 4; ++p) V[n0 + p][d] = av[p];
    }
    __syncthreads();
    if (tid < 64) {
        int m = tid >> 3, n = tid & 7;
        float s = 0.0f;
        for (int c = 0; c < 256; ++c) s = fmaf(QT[c][m], KT[c][n], s);
        S[m][n] = s * (1.0f / 32.0f);
    }
    __syncthreads();
    if (tid < 8) {
        int m = tid;
        float mx = 0.0f;
        for (int n = 0; n < 8; ++n) mx = fmaxf(mx, S[m][n]);
        float en = expf(0.0f - mx);
        float sum = en;
        float e[8];
        for (int n = 0; n < 8; ++n) { e[n] = expf(S[m][n] - mx); sum += e[n]; }
        float inv = 1.0f / sum;
        for (int n = 0; n < 8; ++n) P[m][n] = e[n] * inv;
        nnull[m] = 1.0f - en * inv;
    }
    __syncthreads();
    if (tid == 0) {
        unsigned sel = 0;
        for (int s = 0; s < 4; ++s) {
            int best = 0; float bv = -3.0e38f;
            for (int m = 0; m < 8; ++m)
                if (!(sel & (1u << m)) && nnull[m] > bv) { bv = nnull[m]; best = m; }
            sel |= 1u << best;
        }
        for (int m = 0; m < 8; ++m) maskS[m] = (sel & (1u << m)) ? 1.0f : 0.0f;
    }
    __syncthreads();
    {
        int m = tid >> 5;
        int d0 = (tid & 31) * 4;
        float acc[4] = {0, 0, 0, 0};
#pragma unroll
        for (int n = 0; n < 8; ++n) {
            float p = P[m][n];
#pragma unroll
            for (int q = 0; q < 4; ++q) acc[q] = fmaf(p, V[n][d0 + q], acc[q]);
        }
        float mk = maskS[m];
        reinterpret_cast<float4*>(iu + b * HIDX + m * 128 + d0)[0] =
            make_float4(acc[0] * mk, acc[1] * mk, acc[2] * mk, acc[3] * mk);
    }
    if (tid < 8) {
        maskp[b * 8 + tid] = maskS[tid];
        block_mask[b * 8 + tid] = maskS[tid];
    }
}

// ---------------- K2: shared block GRU via MFMA ----------------
// GRU GEMM unchanged (round-8-verified). NEW: wkey/h_read also via MFMA —
// wave wid computes wkey for t=wid (4 MFMA); wave 0 computes h_read reusing
// the ah[] A-fragments already in registers (4 MFMA). Replaces the 640-iter
// serial FMA chain (the dominant latency-bound phase per round-12 counters).
__global__ __launch_bounds__(256) void k2_gru(
    float* iu /*in: inp_use, out: mask_full (same memory)*/,
    const float* __restrict__ hx,
    const unsigned short* __restrict__ Bpk,
    const unsigned short* __restrict__ Brw,
    const float* __restrict__ b_ih, const float* __restrict__ b_hh,
    const float* __restrict__ maskp,
    float* __restrict__ hnew_out, float* __restrict__ temp_att)
{
    int b0 = blockIdx.x * 2;
    int tid = threadIdx.x;
    __shared__ float hs[16][132];              // fp32 H rows, padded (bank spread)
    __shared__ unsigned short Af[2][4][64][8]; // A-frags [mat x|h][ks][lane][8 bf16]
    __shared__ float hnext[16][516];
    __shared__ float hread[16][16];
    // wkey aliases Af (dead after frag loads): 4 KB <= 8 KB
    float (*wkey)[4][16] = reinterpret_cast<float (*)[4][16]>(&Af[0][0][0][0]);

    // ---- stage: hs fp32, A-fragments bf16, emit mask_full in place ----
#pragma unroll
    for (int it = 0; it < 2; ++it) {
        int idx = tid + it * 256;              // 0..511 float4 slots
        int r = idx >> 5, q = idx & 31;        // row, float4-index (k0 = 4q)
        float4 xv = reinterpret_cast<const float4*>(iu + b0 * HIDX)[idx];
        float4 hv = reinterpret_cast<const float4*>(hx + b0 * HIDX)[idx];
        hs[r][4 * q + 0] = hv.x; hs[r][4 * q + 1] = hv.y;
        hs[r][4 * q + 2] = hv.z; hs[r][4 * q + 3] = hv.w;
        int ks = q >> 3, rem = q & 7, hi = rem >> 2, p = rem & 3;
        int l = p * 16 + r;
        *reinterpret_cast<ushort4*>(&Af[0][ks][l][hi * 4]) =
            make_ushort4(f2bf(xv.x), f2bf(xv.y), f2bf(xv.z), f2bf(xv.w));
        *reinterpret_cast<ushort4*>(&Af[1][ks][l][hi * 4]) =
            make_ushort4(f2bf(hv.x), f2bf(hv.y), f2bf(hv.z), f2bf(hv.w));
        float mkv = maskp[b0 * 8 + r];
        reinterpret_cast<float4*>(iu + b0 * HIDX)[idx] = make_float4(mkv, mkv, mkv, mkv);
    }
    __syncthreads();

    int lane = tid & 63, wid = tid >> 6;
    short8v ax[4], ah[4];
#pragma unroll
    for (int ks = 0; ks < 4; ++ks) {
        ax[ks] = *reinterpret_cast<const short8v*>(&Af[0][ks][lane][0]);
        ah[ks] = *reinterpret_cast<const short8v*>(&Af[1][ks][lane][0]);
    }
    int jl = wid * 32 + (lane & 15);   // j for jt=0 (add 16 for jt=1)
    int rbase = (lane >> 4) * 4;       // C/D: row = rbase + reg, col = lane&15
    int cl = lane & 15;

    for (int t = 0; t < 4; ++t) {
        f32x4 acc[2][6];
#pragma unroll
        for (int jt = 0; jt < 2; ++jt)
#pragma unroll
            for (int g = 0; g < 6; ++g)
                acc[jt][g] = (f32x4){0.f, 0.f, 0.f, 0.f};
#pragma unroll
        for (int ks = 0; ks < 4; ++ks) {
            const unsigned short* pb =
                Bpk + (size_t)((((t * 4 + ks) * 6) * 8 + wid * 2) * 512 + lane * 8);
#pragma unroll
            for (int g = 0; g < 6; ++g) {
                short8v bv0 = *reinterpret_cast<const short8v*>(pb + g * 4096);
                short8v bv1 = *reinterpret_cast<const short8v*>(pb + g * 4096 + 512);
                short8v a = (g < 3) ? ax[ks] : ah[ks];
                acc[0][g] = __builtin_amdgcn_mfma_f32_16x16x32_bf16(a, bv0, acc[0][g], 0, 0, 0);
                acc[1][g] = __builtin_amdgcn_mfma_f32_16x16x32_bf16(a, bv1, acc[1][g], 0, 0, 0);
            }
        }
#pragma unroll
        for (int jt = 0; jt < 2; ++jt) {
            int j = jl + jt * 16;
            float bir = b_ih[t * 384 + j],       bhr = b_hh[t * 384 + j];
            float biz = b_ih[t * 384 + 128 + j], bhz = b_hh[t * 384 + 128 + j];
            float bin = b_ih[t * 384 + 256 + j], bhn = b_hh[t * 384 + 256 + j];
#pragma unroll
            for (int rg = 0; rg < 4; ++rg) {
                int row = rbase + rg;
                float ir  = acc[jt][0][rg] + bir;
                float iz  = acc[jt][1][rg] + biz;
                float inn = acc[jt][2][rg] + bin;
                float hr  = acc[jt][3][rg] + bhr;
                float hz  = acc[jt][4][rg] + bhz;
                float hn  = acc[jt][5][rg] + bhn;
                float rr = sigm(ir + hr);
                float zz = sigm(iz + hz);
                float nn = tanhf(inn + rr * hn);
                hnext[row][t * 128 + j] = (1.0f - zz) * nn + zz * hs[row][j];
            }
        }
    }
    __syncthreads();

    { // ---- wkey (wave wid -> t=wid) + h_read (wave 0) via MFMA ----
        int t = wid;
        short8v an[4];
#pragma unroll
        for (int ks = 0; ks < 4; ++ks) {
            int kb = t * 128 + ks * 32 + 4 * (lane >> 4);
            float4 lo = *reinterpret_cast<const float4*>(&hnext[cl][kb]);
            float4 hi4 = *reinterpret_cast<const float4*>(&hnext[cl][kb + 16]);
            union { ushort4 u4[2]; short8v v; } cvt;
            cvt.u4[0] = make_ushort4(f2bf(lo.x), f2bf(lo.y), f2bf(lo.z), f2bf(lo.w));
            cvt.u4[1] = make_ushort4(f2bf(hi4.x), f2bf(hi4.y), f2bf(hi4.z), f2bf(hi4.w));
            an[ks] = cvt.v;
        }
        f32x4 accw = (f32x4){0.f, 0.f, 0.f, 0.f};
#pragma unroll
        for (int ks = 0; ks < 4; ++ks) {
            short8v bv = *reinterpret_cast<const short8v*>(
                Brw + (size_t)(4 + t * 4 + ks) * 512 + lane * 8);
            accw = __builtin_amdgcn_mfma_f32_16x16x32_bf16(an[ks], bv, accw, 0, 0, 0);
        }
#pragma unroll
        for (int rg = 0; rg < 4; ++rg) wkey[rbase + rg][t][cl] = accw[rg];
        if (wid == 0) {
            f32x4 accr = (f32x4){0.f, 0.f, 0.f, 0.f};
#pragma unroll
            for (int ks = 0; ks < 4; ++ks) {
                short8v bv = *reinterpret_cast<const short8v*>(
                    Brw + (size_t)ks * 512 + lane * 8);
                accr = __builtin_amdgcn_mfma_f32_16x16x32_bf16(ah[ks], bv, accr, 0, 0, 0);
            }
#pragma unroll
            for (int rg = 0; rg < 4; ++rg) hread[rbase + rg][cl] = accr[rg];
        }
    }
    __syncthreads();
    if (tid < 16) { // template softmax; att into hread[r][0..3] (hread cols 4..15 dead now)
        int r = tid;
        float lg[4];
        for (int t = 0; t < 4; ++t) {
            float s = 0.0f;
            for (int k = 0; k < 16; ++k) s = fmaf(hread[r][k], wkey[r][t][k], s);
            lg[t] = s * 0.25f;
        }
        float mx = fmaxf(fmaxf(lg[0], lg[1]), fmaxf(lg[2], lg[3]));
        float e[4], sum = 0.0f;
        for (int t = 0; t < 4; ++t) { e[t] = expf(lg[t] - mx); sum += e[t]; }
        float inv = 1.0f / sum;
        float att[4];
        for (int t = 0; t < 4; ++t) att[t] = e[t] * inv;
        for (int t = 0; t < 4; ++t) {
            hread[r][t] = att[t];
            temp_att[(b0 * 8 + r) * 4 + t] = att[t];
        }
    }
    __syncthreads();
    { // hnew = sum_t att[t] * hnext[t]
        int r = tid >> 4;
        int h0 = (tid & 15) * 8;
        float o[8] = {0, 0, 0, 0, 0, 0, 0, 0};
#pragma unroll
        for (int t = 0; t < 4; ++t) {
            float a = hread[r][t];
#pragma unroll
            for (int q = 0; q < 8; ++q) o[q] = fmaf(a, hnext[r][t * 128 + h0 + q], o[q]);
        }
        float* dst = hnew_out + (b0 + (r >> 3)) * HIDX + (r & 7) * 128 + h0;
        reinterpret_cast<float4*>(dst)[0] = make_float4(o[0], o[1], o[2], o[3]);
        reinterpret_cast<float4*>(dst)[1] = make_float4(o[4], o[5], o[6], o[7]);
    }
}

// ---------------- K3: comm attention + final select via MFMA (unchanged, round-12-verified) ----------------
__global__ __launch_bounds__(256) void k3_comm(
    const float* __restrict__ hx, const float* __restrict__ maskp,
    const unsigned short* __restrict__ Bqkv, const unsigned short* __restrict__ Bfg,
    const float* __restrict__ bq_c, const float* __restrict__ bk_c,
    const float* __restrict__ bv_c, const float* __restrict__ b_fc,
    const float* __restrict__ b_g,
    float* hio)
{
    int b0 = blockIdx.x * 2;
    int tid = threadIdx.x;
    __shared__ float hs[16][132];              // hnew fp32 natural [row][c]
    __shared__ unsigned short Af[4][64][8];    // A-frags: h (qkv), then out (fc/gate)
    __shared__ float qT[128][17];              // [c][row]; later aliased by fco[16][132]
    __shared__ float kT[128][17];              // [c][row]; later aliased by gco[16][132]
    __shared__ float vN[16][132];              // [row][c]
    __shared__ float P[2][4][8][8];            // [b'][ch][m][n]
    float (*fco)[132] = reinterpret_cast<float (*)[132]>(&qT[0][0]);
    float (*gco)[132] = reinterpret_cast<float (*)[132]>(&kT[0][0]);

    // ---- stage hnew: fp32 rows + bf16 A-frags ----
#pragma unroll
    for (int it = 0; it < 2; ++it) {
        int idx = tid + it * 256;
        int r = idx >> 5, q = idx & 31;
        float4 hv = reinterpret_cast<const float4*>(hio + b0 * HIDX)[idx];
        hs[r][4 * q + 0] = hv.x; hs[r][4 * q + 1] = hv.y;
        hs[r][4 * q + 2] = hv.z; hs[r][4 * q + 3] = hv.w;
        int ks = q >> 3, rem = q & 7, hi = rem >> 2, p = rem & 3;
        int l = p * 16 + r;
        *reinterpret_cast<ushort4*>(&Af[ks][l][hi * 4]) =
            make_ushort4(f2bf(hv.x), f2bf(hv.y), f2bf(hv.z), f2bf(hv.w));
    }
    __syncthreads();

    int lane = tid & 63, wid = tid >> 6;
    int rbase = (lane >> 4) * 4;
    int cl = lane & 15;

    { // ---- QKV GEMM: 24 j-tiles over [Wq|Wk|Wv], wave w does jt = w+4u ----
        short8v ah[4];
#pragma unroll
        for (int ks = 0; ks < 4; ++ks)
            ah[ks] = *reinterpret_cast<const short8v*>(&Af[ks][lane][0]);
#pragma unroll
        for (int u = 0; u < 6; ++u) {
            int jt = wid + 4 * u;
            f32x4 acc = (f32x4){0.f, 0.f, 0.f, 0.f};
#pragma unroll
            for (int ks = 0; ks < 4; ++ks) {
                short8v bv = *reinterpret_cast<const short8v*>(
                    Bqkv + (size_t)(ks * 24 + jt) * 512 + lane * 8);
                acc = __builtin_amdgcn_mfma_f32_16x16x32_bf16(ah[ks], bv, acc, 0, 0, 0);
            }
            int mat = jt >> 3;
            int n = ((jt & 7) << 4) + cl;
            if (mat == 0) {
                float bb = bq_c[n];
#pragma unroll
                for (int rg = 0; rg < 4; ++rg) qT[n][rbase + rg] = acc[rg] + bb;
            } else if (mat == 1) {
                float bb = bk_c[n];
#pragma unroll
                for (int rg = 0; rg < 4; ++rg) kT[n][rbase + rg] = acc[rg] + bb;
            } else {
                float bb = bv_c[n];
#pragma unroll
                for (int rg = 0; rg < 4; ++rg) vN[rbase + rg][n] = acc[rg] + bb;
            }
        }
    }
    __syncthreads();

    if (tid < 64) { // ---- per-head scores + softmax (fp32) ----
        int bp = tid >> 5, ch = (tid >> 3) & 3, m = tid & 7;
        int r = bp * 8 + m;
        float s[8] = {0, 0, 0, 0, 0, 0, 0, 0};
        for (int d = 0; d < 32; ++d) {
            float qv = qT[ch * 32 + d][r];
#pragma unroll
            for (int n = 0; n < 8; ++n) s[n] = fmaf(qv, kT[ch * 32 + d][bp * 8 + n], s[n]);
        }
        const float scl = 0.17677669529663687f; // 1/sqrt(32)
        float mx = -3.0e38f;
        for (int n = 0; n < 8; ++n) { s[n] *= scl; mx = fmaxf(mx, s[n]); }
        float e[8], sum = 0.0f;
        for (int n = 0; n < 8; ++n) { e[n] = expf(s[n] - mx); sum += e[n]; }
        float inv = 1.0f / sum;
        for (int n = 0; n < 8; ++n) P[bp][ch][m][n] = e[n] * inv;
    }
    __syncthreads();

    { // ---- PV (fp32) -> write `out` rows directly as bf16 A-frags into Af ----
        int r = tid >> 4, bp = r >> 3, m = r & 7;
        int c0 = (tid & 15) * 8, ch = c0 >> 5;
        float acc[8] = {0, 0, 0, 0, 0, 0, 0, 0};
#pragma unroll
        for (int n = 0; n < 8; ++n) {
            float p = P[bp][ch][m][n];
#pragma unroll
            for (int q = 0; q < 8; ++q) acc[q] = fmaf(p, vN[bp * 8 + n][c0 + q], acc[q]);
        }
        int q0 = (tid & 15) * 2;
#pragma unroll
        for (int dq = 0; dq < 2; ++dq) {
            int qq = q0 + dq;
            int ks = qq >> 3, rem = qq & 7, hi = rem >> 2, p2 = rem & 3;
            int l = p2 * 16 + r;
            *reinterpret_cast<ushort4*>(&Af[ks][l][hi * 4]) =
                make_ushort4(f2bf(acc[dq * 4 + 0]), f2bf(acc[dq * 4 + 1]),
                             f2bf(acc[dq * 4 + 2]), f2bf(acc[dq * 4 + 3]));
        }
    }
    __syncthreads();

    { // ---- fc & gate GEMM: 16 j-tiles over [W_fc|W_g]; fco/gco alias qT/kT ----
        short8v ao2[4];
#pragma unroll
        for (int ks = 0; ks < 4; ++ks)
            ao2[ks] = *reinterpret_cast<const short8v*>(&Af[ks][lane][0]);
#pragma unroll
        for (int u = 0; u < 4; ++u) {
            int jt = wid + 4 * u;
            f32x4 acc = (f32x4){0.f, 0.f, 0.f, 0.f};
#pragma unroll
            for (int ks = 0; ks < 4; ++ks) {
                short8v bv = *reinterpret_cast<const short8v*>(
                    Bfg + (size_t)(ks * 16 + jt) * 512 + lane * 8);
                acc = __builtin_amdgcn_mfma_f32_16x16x32_bf16(ao2[ks], bv, acc, 0, 0, 0);
            }
            int mat = jt >> 3;
            int n = ((jt & 7) << 4) + cl;
            if (mat == 0) {
                float bb = b_fc[n];
#pragma unroll
                for (int rg = 0; rg < 4; ++rg) fco[rbase + rg][n] = acc[rg] + bb;
            } else {
                float bb = b_g[n];
#pragma unroll
                for (int rg = 0; rg < 4; ++rg) gco[rbase + rg][n] = acc[rg] + bb;
            }
        }
    }
    __syncthreads();

    { // ---- final: att_out = sigm(gate)*tanh(fc); hx_out = mask ? hnew+ao : hx ----
        int r = tid >> 4, j0 = (tid & 15) * 8;
        int b = b0 + (r >> 3), m = r & 7;
        float mk = maskp[b * 8 + m];
        float res[8];
#pragma unroll
        for (int q = 0; q < 8; ++q) {
            int jj = j0 + q;
            float ao = sigm(gco[r][jj]) * tanhf(fco[r][jj]);
            float hn = hs[r][jj] + ao;
            float ho = hx[b * HIDX + m * 128 + jj];
            res[q] = mk * hn + (1.0f - mk) * ho;
        }
        float* dst = hio + b * HIDX + m * 128 + j0;
        reinterpret_cast<float4*>(dst)[0] = make_float4(res[0], res[1], res[2], res[3]);
        reinterpret_cast<float4*>(dst)[1] = make_float4(res[4], res[5], res[6], res[7]);
    }
}

// ---------------- launch ----------------
extern "C" void kernel_launch(void* const* d_in, const int* in_sizes, int n_in,
                              void* d_out, int out_size, void* d_ws, size_t ws_size,
                              hipStream_t stream)
{
    const float* inp     = (const float*)d_in[0];
    const float* hx      = (const float*)d_in[1];
    const float* Wq_in   = (const float*)d_in[3];
    const float* Wk_in   = (const float*)d_in[4];
    const float* Wv_in   = (const float*)d_in[5];
    const float* W_ih    = (const float*)d_in[6];
    const float* b_ih    = (const float*)d_in[7];
    const float* W_hh    = (const float*)d_in[8];
    const float* b_hh    = (const float*)d_in[9];
    const float* W_read  = (const float*)d_in[10];
    const float* W_write = (const float*)d_in[11];
    const float* Wq_c    = (const float*)d_in[12];
    const float* bq_c    = (const float*)d_in[13];
    const float* Wk_c    = (const float*)d_in[14];
    const float* bk_c    = (const float*)d_in[15];
    const float* Wv_c    = (const float*)d_in[16];
    const float* bv_c    = (const float*)d_in[17];
    const float* W_fc    = (const float*)d_in[18];
    const float* b_fc    = (const float*)d_in[19];
    const float* W_g     = (const float*)d_in[20];
    const float* b_g     = (const float*)d_in[21];

    float* out        = (float*)d_out;
    float* hx_out     = out;                 // B*1024
    float* mask_full  = out + 4194304;       // B*1024 (also temp home of inp_use)
    float* block_mask = out + 8388608;       // B*8
    float* temp_att   = out + 8421376;       // B*8*4

    float* ws    = (float*)d_ws;
    float* Wvm   = ws;                            // 16384 f
    float* maskp = ws + 16384;                    // 32768 f
    unsigned short* Bpk  = (unsigned short*)(ws + 49152);  // 393216 us
    unsigned short* Bqkv = Bpk + 393216;                   // 49152 us
    unsigned short* Bfg  = Bqkv + 49152;                   // 32768 us
    unsigned short* Brw  = Bfg + 32768;                    // 10240 us
    // total ws: ~1.17 MB

    k0_prep<<<1960, 256, 0, stream>>>(Wv_in, W_ih, W_hh, Wq_c, Wk_c, Wv_c,
                                      W_fc, W_g, W_read, W_write,
                                      Wvm, Bpk, Bqkv, Bfg, Brw);
    k1_input_attn<<<NB, 256, 0, stream>>>(inp, hx, Wq_in, Wk_in, Wvm,
                                          mask_full /*inp_use*/, maskp, block_mask);
    k2_gru<<<NB / 2, 256, 0, stream>>>(mask_full /*inp_use -> mask_full*/, hx,
                                       Bpk, Brw, b_ih, b_hh,
                                       maskp, hx_out /*hnew*/, temp_att);
    k3_comm<<<NB / 2, 256, 0, stream>>>(hx, maskp, Bqkv, Bfg,
                                        bq_c, bk_c, bv_c, b_fc, b_g, hx_out);
}